// Round 10
// baseline (640.816 us; speedup 1.0000x reference)
//
#include <hip/hip_runtime.h>
#include <hip/hip_bf16.h>
#include <math.h>

// RGSLCell on MI355X. R18 = R17 + cheb-GEMM K-split (occupancy fix):
//  Both cheb GEMMs were grid-limited to 1 block/CU (256 blocks) -> every
//  barrier stalled the CU (2 waves/SIMD, MfmaUtil 32%). R18 splits K across
//  blockIdx.z=2 (each half K=1536, fp32 partials; half 1 -> scratch in the
//  dead Zbuf/t12 region). Gate k3w additionally BK 64->32 so LDS 96->48KB
//  (2 blocks/CU capacity). Readers fold the partial: lrelu(a1 + p1).
//  Numerics: each half keeps its exact ascending K-chain; only the final
//  fp32 half-sum is reassociated (~2^-24) - invisible vs the bf16 floor.
// Everything else identical to R17 (631.2us, absmax 0.078125).

#define B_  64
#define N_  1024
#define CIN_ 96
#define R_  288

typedef __attribute__((ext_vector_type(8))) short bf16x8;
typedef __attribute__((ext_vector_type(4))) float f32x4;
typedef unsigned short u16;
typedef unsigned int u32;

__device__ __forceinline__ float lrelu(float v) { return v >= 0.f ? v : 0.01f * v; }
__device__ __forceinline__ float sigmoidf_(float u) { return 1.f / (1.f + expf(-u)); }
// round-to-nearest-even fp32 -> bf16
__device__ __forceinline__ u16 f2b(float f) {
  union { float f; u32 u; } c; c.f = f;
  u32 u = c.u;
  return (u16)((u + 0x7FFFu + ((u >> 16) & 1u)) >> 16);
}
__device__ __forceinline__ float b2f(u16 u) {
  union { u32 x; float f; } c; c.x = ((u32)u) << 16; return c.f;
}
__device__ __forceinline__ void gload_lds16(const u16* gp, u16* lp) {
  __builtin_amdgcn_global_load_lds((const __attribute__((address_space(1))) u32*)gp,
                                   (__attribute__((address_space(3))) u32*)lp, 16, 0, 0);
}

// ---------------------------------------------------------------------------
// concat: inp fp32 AND inpb bf16, layout [(n*64+b)][96]
__global__ __launch_bounds__(256) void concat_bf2(const float* __restrict__ x,
                                                  const float* __restrict__ st,
                                                  float* __restrict__ inp,
                                                  u16* __restrict__ inpb) {
  size_t t = (size_t)blockIdx.x * 256 + threadIdx.x;
  if (t >= (size_t)B_ * N_ * CIN_) return;
  int i = (int)(t % CIN_);
  size_t v = t / CIN_;
  size_t b = v & 63, n = v >> 6;
  float f = (i < 32) ? x[(b * N_ + n) * 32 + i] : st[(b * N_ + n) * 64 + (i - 32)];
  inp[t] = f;
  inpb[t] = f2b(f);
}

// fp32 -> bf16 flat convert (cheb)
__global__ __launch_bounds__(256) void conv_f2b(const float* __restrict__ in,
                                                u16* __restrict__ out, int n4) {
  int t = blockIdx.x * 256 + threadIdx.x;
  if (t >= n4) return;
  float4 v = ((const float4*)in)[t];
  ushort4 o;
  o.x = f2b(v.x); o.y = f2b(v.y); o.z = f2b(v.z); o.w = f2b(v.w);
  ((ushort4*)out)[t] = o;
}

// split fp32 -> (hi, lo) bf16 planes
__global__ __launch_bounds__(256) void split_hilo(const float* __restrict__ in,
                                                  u16* __restrict__ hi,
                                                  u16* __restrict__ lo, int n4) {
  int t = blockIdx.x * 256 + threadIdx.x;
  if (t >= n4) return;
  float4 v = ((const float4*)in)[t];
  ushort4 h, l;
  h.x = f2b(v.x); l.x = f2b(v.x - b2f(h.x));
  h.y = f2b(v.y); l.y = f2b(v.y - b2f(h.y));
  h.z = f2b(v.z); l.z = f2b(v.z - b2f(h.z));
  h.w = f2b(v.w); l.w = f2b(v.w - b2f(h.w));
  ((ushort4*)hi)[t] = h;
  ((ushort4*)lo)[t] = l;
}

// transpose fp32 [1024][1024] -> (hiT, loT) bf16 planes of L^T
__global__ __launch_bounds__(256) void transpose_split(const float* __restrict__ in,
                                                       u16* __restrict__ hiT,
                                                       u16* __restrict__ loT) {
  __shared__ float t[32][33];
  const int tid = threadIdx.x;
  const int j0 = blockIdx.x * 32, r0 = blockIdx.y * 32;
  const int tc = tid & 31, tr = tid >> 5;
#pragma unroll
  for (int q = 0; q < 4; ++q)
    t[tr + q * 8][tc] = in[(size_t)(r0 + tr + q * 8) * 1024 + j0 + tc];
  __syncthreads();
  const int jj = tid >> 3, rq = (tid & 7) * 4;
  ushort4 h, l;
#pragma unroll
  for (int q = 0; q < 4; ++q) {
    float v = t[rq + q][jj];
    u16 hh = f2b(v);
    ((u16*)&h)[q] = hh;
    ((u16*)&l)[q] = f2b(v - b2f(hh));
  }
  *(ushort4*)(hiT + (size_t)(j0 + jj) * N_ + r0 + rq) = h;
  *(ushort4*)(loT + (size_t)(j0 + jj) * N_ + r0 + rq) = l;
}

// transpose bf16 [(n*64+b)][Zs] -> bf16 [(b*Ctot+c)][1024]
__global__ __launch_bounds__(256) void transpose_b2b(const u16* __restrict__ Z, int Zs,
                                                     int Ctot, u16* __restrict__ Zt) {
  __shared__ u16 t[32][36];
  const int tid = threadIdx.x;
  const int c0 = blockIdx.x * 32, n0 = blockIdx.y * 32, b = blockIdx.z;
  {
    const int i = tid >> 3, c4 = (tid & 7) * 4;
    ushort4 v = *(const ushort4*)(Z + ((size_t)(n0 + i) * 64 + b) * Zs + c0 + c4);
    t[i][c4] = v.x; t[i][c4 + 1] = v.y; t[i][c4 + 2] = v.z; t[i][c4 + 3] = v.w;
  }
  __syncthreads();
  {
    const int c = tid >> 3, n4 = (tid & 7) * 4;
    ushort4 o;
    o.x = t[n4][c]; o.y = t[n4 + 1][c]; o.z = t[n4 + 2][c]; o.w = t[n4 + 3][c];
    *(ushort4*)(Zt + (size_t)(b * Ctot + c0 + c) * 1024 + n0 + n4) = o;
  }
}

// wpool transpose: wpT[d][o][r] = wp[d][r][o]. grid (288/32, OW/32, 16).
__global__ __launch_bounds__(256) void wpool_tr(const float* __restrict__ wp,
                                                float* __restrict__ wpT, int OW) {
  __shared__ float t[32][33];
  const int tid = threadIdx.x;
  const int r0 = blockIdx.x * 32, o0 = blockIdx.y * 32, d = blockIdx.z;
  const size_t base = (size_t)d * 288 * OW;
  const int c = tid & 31, q0 = tid >> 5;
#pragma unroll
  for (int q = 0; q < 4; ++q)
    t[q0 + q * 8][c] = wp[base + (size_t)(r0 + q0 + q * 8) * OW + o0 + c];
  __syncthreads();
#pragma unroll
  for (int q = 0; q < 4; ++q)
    wpT[base + (size_t)(o0 + q0 + q * 8) * 288 + r0 + c] = t[c][q0 + q * 8];
}

// ---------------------------------------------------------------------------
// compensated L2, phase-split: P[z] = (z==0 ? Lhi@Lhi : z==1 ? Llo@Lhi : Lhi@Llo)
__global__ __launch_bounds__(256) void mfma_l2p(const u16* __restrict__ Lhi,
                                                const u16* __restrict__ Llo,
                                                const u16* __restrict__ LhiT,
                                                const u16* __restrict__ LloT,
                                                float* __restrict__ P) {
  __shared__ u16 Asl[64 * 64];
  __shared__ u16 Bsl[64 * 64];
  const int tid = threadIdx.x;
  const int w = tid >> 6, lane = tid & 63;
  const int m0 = blockIdx.y * 64, n0 = blockIdx.x * 64;
  const int ph = blockIdx.z;
  const int wr = w >> 1, wc = w & 1;
  const int sr = lane >> 3, so = lane & 7;
  const int cl = lane & 15, q4 = lane >> 4;
  f32x4 acc[2][2] = {};

  const u16* A = (ph == 1) ? Llo : Lhi;
  const u16* B = (ph == 2) ? LloT : LhiT;
  for (int k0 = 0; k0 < 1024; k0 += 64) {
    __syncthreads();
#pragma unroll
    for (int i = 0; i < 2; ++i) {
      const int r = i * 32 + w * 8 + sr;
      const int o = so ^ (r & 7);
      gload_lds16(A + (size_t)(m0 + r) * 1024 + k0 + o * 8, Asl + (i * 32 + w * 8) * 64);
      gload_lds16(B + (size_t)(n0 + r) * 1024 + k0 + o * 8, Bsl + (i * 32 + w * 8) * 64);
    }
    __syncthreads();
#pragma unroll
    for (int kk = 0; kk < 2; ++kk) {
      bf16x8 af[2], bfr[2];
#pragma unroll
      for (int mi = 0; mi < 2; ++mi) {
        const int ra = wr * 32 + mi * 16 + cl;
        af[mi] = *(const bf16x8*)(Asl + ra * 64 + ((kk * 4 + q4) ^ (ra & 7)) * 8);
      }
#pragma unroll
      for (int ni = 0; ni < 2; ++ni) {
        const int rb = wc * 32 + ni * 16 + cl;
        bfr[ni] = *(const bf16x8*)(Bsl + rb * 64 + ((kk * 4 + q4) ^ (rb & 7)) * 8);
      }
#pragma unroll
      for (int mi = 0; mi < 2; ++mi)
#pragma unroll
        for (int ni = 0; ni < 2; ++ni)
          acc[mi][ni] = __builtin_amdgcn_mfma_f32_16x16x32_bf16(af[mi], bfr[ni], acc[mi][ni], 0, 0, 0);
    }
  }
  float* Pz = P + ((size_t)ph << 20);
#pragma unroll
  for (int mi = 0; mi < 2; ++mi)
#pragma unroll
    for (int ni = 0; ni < 2; ++ni) {
      const int j = n0 + wc * 32 + ni * 16 + cl;
#pragma unroll
      for (int r = 0; r < 4; ++r) {
        const int m = m0 + wr * 32 + mi * 16 + q4 * 4 + r;
        Pz[(size_t)m * 1024 + j] = acc[mi][ni][r];
      }
    }
}

// combine the 3 partials: Y = bf16(2*(P0+P1+P2) - I)
__global__ __launch_bounds__(256) void l2_finish(const float* __restrict__ P,
                                                 u16* __restrict__ Y) {
  int t = blockIdx.x * 256 + threadIdx.x;   // 262144 float4 groups
  float4 a = ((const float4*)P)[t];
  float4 b = ((const float4*)(P + 1048576))[t];
  float4 c = ((const float4*)(P + 2097152))[t];
  int e = t << 2;
  int m = e >> 10, j = e & 1023;
  ushort4 o;
  o.x = f2b(2.f * (a.x + b.x + c.x) - (m == j     ? 1.f : 0.f));
  o.y = f2b(2.f * (a.y + b.y + c.y) - (m == j + 1 ? 1.f : 0.f));
  o.z = f2b(2.f * (a.z + b.z + c.z) - (m == j + 2 ? 1.f : 0.f));
  o.w = f2b(2.f * (a.w + b.w + c.w) - (m == j + 3 ? 1.f : 0.f));
  ((ushort4*)Y)[t] = o;
}

// ---------------------------------------------------------------------------
// wide-tile stack GEMM: Y[2048][J] = A@B, A bf16 [2048][1024], Bt bf16 [J][1024].
// 128(M)x256(N), 8 waves 2x2, 64x64/wave acc[4][4]. LDS 96 KB, vmcnt(6).
__global__ __launch_bounds__(512) void mfma_stack_w(const u16* __restrict__ A,
                                                    const u16* __restrict__ Bt,
                                                    float* __restrict__ Y, int J) {
  __shared__ u16 Asl[2][128 * 64];
  __shared__ u16 Bsl[2][256 * 64];
  const int tid = threadIdx.x;
  const int w = tid >> 6, lane = tid & 63;    // w 0..7
  const int m0 = blockIdx.y * 128, n0 = blockIdx.x * 256;
  const int wr = w >> 2, wc = w & 3;          // wr 0..1 (64-row), wc 0..3 (64-col)
  const int sr = lane >> 3, so = lane & 7;
  const int cl = lane & 15, q4 = lane >> 4;
  f32x4 acc[4][4] = {};

  auto STAGE = [&](u16* Ad, u16* Bd, int k0) {
#pragma unroll
    for (int i = 0; i < 2; ++i) {
      const int r = i * 64 + w * 8 + sr;
      const int o = so ^ (r & 7);
      gload_lds16(A + (size_t)(m0 + r) * 1024 + k0 + o * 8, Ad + (i * 64 + w * 8) * 64);
    }
#pragma unroll
    for (int i = 0; i < 4; ++i) {
      const int r = i * 64 + w * 8 + sr;
      const int o = so ^ (r & 7);
      gload_lds16(Bt + (size_t)(n0 + r) * 1024 + k0 + o * 8, Bd + (i * 64 + w * 8) * 64);
    }
  };
  auto COMPUTE = [&](const u16* As, const u16* Bs) {
#pragma unroll
    for (int kk = 0; kk < 2; ++kk) {
      bf16x8 af[4], bfr[4];
#pragma unroll
      for (int mi = 0; mi < 4; ++mi) {
        const int ra = wr * 64 + mi * 16 + cl;
        af[mi] = *(const bf16x8*)(As + ra * 64 + ((kk * 4 + q4) ^ (ra & 7)) * 8);
      }
#pragma unroll
      for (int ni = 0; ni < 4; ++ni) {
        const int rb = wc * 64 + ni * 16 + cl;
        bfr[ni] = *(const bf16x8*)(Bs + rb * 64 + ((kk * 4 + q4) ^ (rb & 7)) * 8);
      }
#pragma unroll
      for (int mi = 0; mi < 4; ++mi)
#pragma unroll
        for (int ni = 0; ni < 4; ++ni)
          acc[mi][ni] = __builtin_amdgcn_mfma_f32_16x16x32_bf16(af[mi], bfr[ni], acc[mi][ni], 0, 0, 0);
    }
  };

  STAGE(Asl[0], Bsl[0], 0);
  for (int k0 = 0; k0 < 1024; k0 += 128) {
    STAGE(Asl[1], Bsl[1], k0 + 64);
    asm volatile("s_waitcnt vmcnt(6)" ::: "memory");
    __builtin_amdgcn_s_barrier();
    __builtin_amdgcn_sched_barrier(0);
    COMPUTE(Asl[0], Bsl[0]);
    asm volatile("s_waitcnt lgkmcnt(0)" ::: "memory");
    __builtin_amdgcn_s_barrier();
    __builtin_amdgcn_sched_barrier(0);
    if (k0 + 128 < 1024) {
      STAGE(Asl[0], Bsl[0], k0 + 128);
      asm volatile("s_waitcnt vmcnt(6)" ::: "memory");
    } else {
      asm volatile("s_waitcnt vmcnt(0)" ::: "memory");
    }
    __builtin_amdgcn_s_barrier();
    __builtin_amdgcn_sched_barrier(0);
    COMPUTE(Asl[1], Bsl[1]);
    asm volatile("s_waitcnt lgkmcnt(0)" ::: "memory");
    __builtin_amdgcn_s_barrier();
    __builtin_amdgcn_sched_barrier(0);
  }
#pragma unroll
  for (int mi = 0; mi < 4; ++mi)
#pragma unroll
    for (int ni = 0; ni < 4; ++ni) {
      const int j = n0 + wc * 64 + ni * 16 + cl;
#pragma unroll
      for (int r = 0; r < 4; ++r) {
        const int m = m0 + wr * 64 + mi * 16 + q4 * 4 + r;
        Y[(size_t)m * J + j] = acc[mi][ni][r];
      }
    }
}

// ---------------------------------------------------------------------------
// vgen2: one block per output row c.
template <int O, int OSH>
__global__ __launch_bounds__(128) void vgen2(const float* __restrict__ gw,
                                             const float* __restrict__ iw,
                                             const float* __restrict__ ib,
                                             int Ctot,
                                             u16* __restrict__ Vb,
                                             float* __restrict__ ball) {
  const int c = blockIdx.x;
  const int col = threadIdx.x;
  if (c >= Ctot) {  // zero-pad (block-uniform branch)
    if (col < 96) Vb[(size_t)c * 96 + col] = 0;
    else if (col == 96) ball[c] = 0.f;
    return;
  }
  __shared__ float sg[O];
  const int o = c & (O - 1), k = c >> OSH;
  const float* g = gw + (size_t)o * (3 * O) + (size_t)k * O;
  for (int e = col; e < O; e += 128) sg[e] = g[e];
  __syncthreads();
  if (col < 96) {
    float s = 0.f;
#pragma unroll
    for (int j = 0; j < O; ++j) s += sg[j] * iw[j * 96 + col];
    Vb[(size_t)c * 96 + col] = f2b(s);
  } else if (col == 96) {
    float s = 0.f;
#pragma unroll
    for (int j = 0; j < O; ++j) s += sg[j] * ib[j];
    ball[c] = s;
  }
}

// ---------------------------------------------------------------------------
// zgemm: Z[M][Zs] bf16 = A[M][96] @ Vb^T + ball. 128x128 tile, BK=32 x 3.
__global__ __launch_bounds__(256) void zgemm(const u16* __restrict__ A,
                                             const u16* __restrict__ Bt,
                                             const float* __restrict__ ball,
                                             u16* __restrict__ Z, int Zs) {
  __shared__ u16 Asl[128 * 32];
  __shared__ u16 Bsl[128 * 32];
  const int tid = threadIdx.x;
  const int w = tid >> 6, lane = tid & 63;
  const int m0 = blockIdx.y * 128, n0 = blockIdx.x * 128;
  const int wr = w >> 1, wc = w & 1;
  const int sr = lane >> 2, so = lane & 3;
  const int cl = lane & 15, q4 = lane >> 4;
  f32x4 acc[4][4] = {};
  for (int k0 = 0; k0 < 96; k0 += 32) {
    __syncthreads();
#pragma unroll
    for (int i = 0; i < 2; ++i) {
      const int r = i * 64 + w * 16 + sr;
      const int o = so ^ (r & 3);
      gload_lds16(A + (size_t)(m0 + r) * 96 + k0 + o * 8, Asl + (i * 64 + w * 16) * 32);
      gload_lds16(Bt + (size_t)(n0 + r) * 96 + k0 + o * 8, Bsl + (i * 64 + w * 16) * 32);
    }
    __syncthreads();
    bf16x8 af[4], bfr[4];
#pragma unroll
    for (int mi = 0; mi < 4; ++mi) {
      const int ra = wr * 64 + mi * 16 + cl;
      af[mi] = *(const bf16x8*)(Asl + ra * 32 + (q4 ^ (ra & 3)) * 8);
    }
#pragma unroll
    for (int ni = 0; ni < 4; ++ni) {
      const int rb = wc * 64 + ni * 16 + cl;
      bfr[ni] = *(const bf16x8*)(Bsl + rb * 32 + (q4 ^ (rb & 3)) * 8);
    }
#pragma unroll
    for (int mi = 0; mi < 4; ++mi)
#pragma unroll
      for (int ni = 0; ni < 4; ++ni)
        acc[mi][ni] = __builtin_amdgcn_mfma_f32_16x16x32_bf16(af[mi], bfr[ni], acc[mi][ni], 0, 0, 0);
  }
#pragma unroll
  for (int mi = 0; mi < 4; ++mi)
#pragma unroll
    for (int ni = 0; ni < 4; ++ni) {
      const int c = n0 + wc * 64 + ni * 16 + cl;
      const float bb = ball[c];
#pragma unroll
      for (int r = 0; r < 4; ++r) {
        const int m = m0 + wr * 64 + mi * 16 + q4 * 4 + r;
        Z[(size_t)m * Zs + c] = f2b(acc[mi][ni][r] + bb);
      }
    }
}

// ---------------------------------------------------------------------------
// K-split stacked-K cheb GEMM (UPDATE, J=4096): 128x128, 8 waves (2x4),
// acc[4][2], 64 KB LDS. blockIdx.z = K-half (0: +bias -> Y; 1: -> P1).
// Grid (32,8,2) = 512 blocks -> 2 blocks/CU.
__global__ __launch_bounds__(512) void mfma_k3s(const u16* __restrict__ A3,
                                                const u16* __restrict__ Zt,
                                                const float* __restrict__ gb,
                                                float* __restrict__ Y,
                                                float* __restrict__ P1,
                                                int J, int obits) {
  __shared__ u16 Asl[2][128 * 64];
  __shared__ u16 Bsl[2][128 * 64];
  const int tid = threadIdx.x;
  const int w = tid >> 6, lane = tid & 63;
  const int m0 = blockIdx.y * 128, n0 = blockIdx.x * 128;
  const int kh = blockIdx.z;
  const int wr = w >> 2, wc = w & 3;
  const int sr = lane >> 3, so = lane & 7;
  const int cl = lane & 15, q4 = lane >> 4;
  const int omask = (1 << obits) - 1;
  f32x4 acc[4][2] = {};

  auto STAGE = [&](u16* Ad, u16* Bd, int kg) {
    const int kb = kg >> 10, ko = kg & 1023;
#pragma unroll
    for (int i = 0; i < 2; ++i) {
      const int r = i * 64 + w * 8 + sr;
      const int o = so ^ (r & 7);
      gload_lds16(A3 + (size_t)kb * 1048576 + (size_t)(m0 + r) * 1024 + ko + o * 8,
                  Ad + (i * 64 + w * 8) * 64);
      const int jp = n0 + r;
      const int brow = (((jp >> obits) * 3 + kb) << obits) | (jp & omask);
      gload_lds16(Zt + (size_t)brow * 1024 + ko + o * 8, Bd + (i * 64 + w * 8) * 64);
    }
  };
  auto COMPUTE = [&](const u16* As, const u16* Bs) {
#pragma unroll
    for (int kk = 0; kk < 2; ++kk) {
      bf16x8 af[4], bfr[2];
#pragma unroll
      for (int mi = 0; mi < 4; ++mi) {
        const int ra = wr * 64 + mi * 16 + cl;
        af[mi] = *(const bf16x8*)(As + ra * 64 + ((kk * 4 + q4) ^ (ra & 7)) * 8);
      }
#pragma unroll
      for (int ni = 0; ni < 2; ++ni) {
        const int rb = wc * 32 + ni * 16 + cl;
        bfr[ni] = *(const bf16x8*)(Bs + rb * 64 + ((kk * 4 + q4) ^ (rb & 7)) * 8);
      }
#pragma unroll
      for (int mi = 0; mi < 4; ++mi)
#pragma unroll
        for (int ni = 0; ni < 2; ++ni)
          acc[mi][ni] = __builtin_amdgcn_mfma_f32_16x16x32_bf16(af[mi], bfr[ni], acc[mi][ni], 0, 0, 0);
    }
  };

  const int kbase = kh * 1536;
  STAGE(Asl[0], Bsl[0], kbase);
  for (int k0 = 0; k0 < 1536; k0 += 128) {
    STAGE(Asl[1], Bsl[1], kbase + k0 + 64);
    asm volatile("s_waitcnt vmcnt(4)" ::: "memory");
    __builtin_amdgcn_s_barrier();
    __builtin_amdgcn_sched_barrier(0);
    COMPUTE(Asl[0], Bsl[0]);
    asm volatile("s_waitcnt lgkmcnt(0)" ::: "memory");
    __builtin_amdgcn_s_barrier();
    __builtin_amdgcn_sched_barrier(0);
    if (k0 + 128 < 1536) {
      STAGE(Asl[0], Bsl[0], kbase + k0 + 128);
      asm volatile("s_waitcnt vmcnt(4)" ::: "memory");
    } else {
      asm volatile("s_waitcnt vmcnt(0)" ::: "memory");
    }
    __builtin_amdgcn_s_barrier();
    __builtin_amdgcn_sched_barrier(0);
    COMPUTE(Asl[1], Bsl[1]);
    asm volatile("s_waitcnt lgkmcnt(0)" ::: "memory");
    __builtin_amdgcn_s_barrier();
    __builtin_amdgcn_sched_barrier(0);
  }
#pragma unroll
  for (int mi = 0; mi < 4; ++mi)
#pragma unroll
    for (int ni = 0; ni < 2; ++ni) {
      const int j = n0 + wc * 32 + ni * 16 + cl;
      const float bb = (kh == 0) ? gb[j & omask] : 0.f;
      float* dst = (kh == 0) ? Y : P1;
#pragma unroll
      for (int r = 0; r < 4; ++r) {
        const int m = m0 + wr * 64 + mi * 16 + q4 * 4 + r;
        dst[(size_t)m * J + j] = acc[mi][ni][r] + bb;
      }
    }
}

// ---------------------------------------------------------------------------
// K-split wide-tile cheb GEMM (GATE, J=8192): 128(M)x256(N), 8 waves 2x2,
// acc[4][4], BK=32 -> LDS 48 KB (2 blocks/CU). blockIdx.z = K-half.
// Grid (32,8,2) = 512 blocks. 3 gloads/thread -> counted vmcnt(3).
__global__ __launch_bounds__(512) void mfma_k3ws(const u16* __restrict__ A3,
                                                 const u16* __restrict__ Zt,
                                                 const float* __restrict__ gb,
                                                 float* __restrict__ Y,
                                                 float* __restrict__ P1,
                                                 int J, int obits) {
  __shared__ u16 Asl[2][128 * 32];
  __shared__ u16 Bsl[2][256 * 32];
  const int tid = threadIdx.x;
  const int w = tid >> 6, lane = tid & 63;
  const int m0 = blockIdx.y * 128, n0 = blockIdx.x * 256;
  const int kh = blockIdx.z;
  const int wr = w >> 2, wc = w & 3;
  const int rr = lane >> 2, seg = lane & 3;   // staging: 4 lanes/row (32-u16 rows)
  const int cl = lane & 15, q4 = lane >> 4;
  const int omask = (1 << obits) - 1;
  f32x4 acc[4][4] = {};

  auto STAGE = [&](u16* Ad, u16* Bd, int kg) {
    const int kb = kg >> 10, ko = kg & 1023;
    {
      const int r = w * 16 + rr;
      const int o = seg ^ (r & 3);
      gload_lds16(A3 + (size_t)kb * 1048576 + (size_t)(m0 + r) * 1024 + ko + o * 8,
                  Ad + w * 512);
    }
#pragma unroll
    for (int i = 0; i < 2; ++i) {
      const int r = i * 128 + w * 16 + rr;
      const int o = seg ^ (r & 3);
      const int jp = n0 + r;
      const int brow = (((jp >> obits) * 3 + kb) << obits) | (jp & omask);
      gload_lds16(Zt + (size_t)brow * 1024 + ko + o * 8, Bd + i * 4096 + w * 512);
    }
  };
  auto COMPUTE = [&](const u16* As, const u16* Bs) {
    bf16x8 af[4], bfr[4];
#pragma unroll
    for (int mi = 0; mi < 4; ++mi) {
      const int ra = wr * 64 + mi * 16 + cl;
      af[mi] = *(const bf16x8*)(As + ra * 32 + ((q4 ^ (ra & 3)) * 8));
    }
#pragma unroll
    for (int ni = 0; ni < 4; ++ni) {
      const int rb = wc * 64 + ni * 16 + cl;
      bfr[ni] = *(const bf16x8*)(Bs + rb * 32 + ((q4 ^ (rb & 3)) * 8));
    }
#pragma unroll
    for (int mi = 0; mi < 4; ++mi)
#pragma unroll
      for (int ni = 0; ni < 4; ++ni)
        acc[mi][ni] = __builtin_amdgcn_mfma_f32_16x16x32_bf16(af[mi], bfr[ni], acc[mi][ni], 0, 0, 0);
  };

  const int kbase = kh * 1536;
  STAGE(Asl[0], Bsl[0], kbase);
  for (int k0 = 0; k0 < 1536; k0 += 64) {
    STAGE(Asl[1], Bsl[1], kbase + k0 + 32);
    asm volatile("s_waitcnt vmcnt(3)" ::: "memory");
    __builtin_amdgcn_s_barrier();
    __builtin_amdgcn_sched_barrier(0);
    COMPUTE(Asl[0], Bsl[0]);
    asm volatile("s_waitcnt lgkmcnt(0)" ::: "memory");
    __builtin_amdgcn_s_barrier();
    __builtin_amdgcn_sched_barrier(0);
    if (k0 + 64 < 1536) {
      STAGE(Asl[0], Bsl[0], kbase + k0 + 64);
      asm volatile("s_waitcnt vmcnt(3)" ::: "memory");
    } else {
      asm volatile("s_waitcnt vmcnt(0)" ::: "memory");
    }
    __builtin_amdgcn_s_barrier();
    __builtin_amdgcn_sched_barrier(0);
    COMPUTE(Asl[1], Bsl[1]);
    asm volatile("s_waitcnt lgkmcnt(0)" ::: "memory");
    __builtin_amdgcn_s_barrier();
    __builtin_amdgcn_sched_barrier(0);
  }
#pragma unroll
  for (int mi = 0; mi < 4; ++mi)
#pragma unroll
    for (int ni = 0; ni < 4; ++ni) {
      const int j = n0 + wc * 64 + ni * 16 + cl;
      const float bb = (kh == 0) ? gb[j & omask] : 0.f;
      float* dst = (kh == 0) ? Y : P1;
#pragma unroll
      for (int r = 0; r < 4; ++r) {
        const int m = m0 + wr * 64 + mi * 16 + q4 * 4 + r;
        dst[(size_t)m * J + j] = acc[mi][ni][r] + bb;
      }
    }
}

// ---------------------------------------------------------------------------
// weightgen5: Wt[n][SZ] bf16 = sum_d emb[n][d]*wpoolT[d][SZ] (linear; SZ=OW*288)
template <int SZ>
__global__ __launch_bounds__(256) void weightgen5(const float* __restrict__ emb,
                                                  const float* __restrict__ wpT,
                                                  u16* __restrict__ W) {
  const int tid = threadIdx.x;
  const int ro = blockIdx.x * 256 + tid;
  const int n0 = blockIdx.y * 64;
  __shared__ float semb[64][17];
  for (int e = tid; e < 1024; e += 256) semb[e >> 4][e & 15] = emb[(n0 + (e >> 4)) * 16 + (e & 15)];
  __syncthreads();
  float wv[16];
#pragma unroll
  for (int d = 0; d < 16; ++d) wv[d] = wpT[(size_t)d * SZ + ro];
#pragma unroll 4
  for (int n = 0; n < 64; ++n) {
    float s = 0.f;
#pragma unroll
    for (int d = 0; d < 16; ++d) s += semb[n][d] * wv[d];
    W[(size_t)(n0 + n) * SZ + ro] = f2b(s);
  }
}

// pernode10: per-node GEMM on the MATRIX pipe. Block per node, 4 waves.
// C[o][b] = Wt[n] @ X^T. X fp32 -> hi/lo bf16 in LDS. 9 chunks x {hi,lo}.
template <int OW>
__global__ __launch_bounds__(256) void pernode10(const float* __restrict__ xa,
                                                 const float* __restrict__ xbc,
                                                 const u16* __restrict__ Wt,
                                                 const float* __restrict__ emb,
                                                 const float* __restrict__ bpool,
                                                 float* __restrict__ outp) {
  constexpr int MT = OW / 64;            // o 16-tiles per wave (2 gate, 1 upd)
  const int n = blockIdx.x;
  const int tid = threadIdx.x;
  const int w = tid >> 6, lane = tid & 63;
  const int cl = lane & 15, q4 = lane >> 4;
  __shared__ u16 sWt[OW * 32];
  __shared__ u16 sXh[64 * 32];
  __shared__ u16 sXl[64 * 32];
  __shared__ float semb[16];
  if (tid < 16) semb[tid] = emb[n * 16 + tid];
  f32x4 acc[MT][4] = {};
  const u16* Wn = Wt + (size_t)n * (OW * 288);
  const int xb = tid >> 2, rg = tid & 3;  // X staging map: b row, 8-r group

  for (int c = 0; c < 9; ++c) {
    const int k = c / 3, i0 = (c % 3) * 32;
    const float* xk = (k == 0) ? (xa + (size_t)n * 6144)
                               : (xbc + ((size_t)(k - 1) * 1024 + n) * 6144);
    __syncthreads();
#pragma unroll
    for (int i = 0; i < MT; ++i) {
      const int g = w * MT + i;                  // 16-row group
      const int o = g * 16 + (lane >> 2);
      const int seg = (lane & 3) ^ (o & 3);
      gload_lds16(Wn + (size_t)o * 288 + c * 32 + seg * 8, sWt + g * 512);
    }
    {
      const float* p = xk + (size_t)xb * 96 + i0 + rg * 8;
      float4 v0 = *(const float4*)p;
      float4 v1 = *(const float4*)(p + 4);
      float xv[8] = {v0.x, v0.y, v0.z, v0.w, v1.x, v1.y, v1.z, v1.w};
      bf16x8 h, l;
#pragma unroll
      for (int j = 0; j < 8; ++j) {
        u16 hh = f2b(xv[j]);
        ((u16*)&h)[j] = hh;
        ((u16*)&l)[j] = f2b(xv[j] - b2f(hh));
      }
      const int col = (rg ^ (xb & 3)) * 8;
      *(bf16x8*)(sXh + xb * 32 + col) = h;
      *(bf16x8*)(sXl + xb * 32 + col) = l;
    }
    __syncthreads();
    bf16x8 aw[MT], bh[4], bl[4];
#pragma unroll
    for (int mi = 0; mi < MT; ++mi) {
      const int o = (w * MT + mi) * 16 + cl;
      aw[mi] = *(const bf16x8*)(sWt + o * 32 + ((q4 ^ (o & 3)) * 8));
    }
#pragma unroll
    for (int ni = 0; ni < 4; ++ni) {
      const int b = ni * 16 + cl;
      const int col = (q4 ^ (b & 3)) * 8;
      bh[ni] = *(const bf16x8*)(sXh + b * 32 + col);
      bl[ni] = *(const bf16x8*)(sXl + b * 32 + col);
    }
#pragma unroll
    for (int mi = 0; mi < MT; ++mi)
#pragma unroll
      for (int ni = 0; ni < 4; ++ni)
        acc[mi][ni] = __builtin_amdgcn_mfma_f32_16x16x32_bf16(aw[mi], bh[ni], acc[mi][ni], 0, 0, 0);
#pragma unroll
    for (int mi = 0; mi < MT; ++mi)
#pragma unroll
      for (int ni = 0; ni < 4; ++ni)
        acc[mi][ni] = __builtin_amdgcn_mfma_f32_16x16x32_bf16(aw[mi], bl[ni], acc[mi][ni], 0, 0, 0);
  }
  float4 biasv[MT];
#pragma unroll
  for (int mi = 0; mi < MT; ++mi)
#pragma unroll
    for (int r = 0; r < 4; ++r) {
      const int o = (w * MT + mi) * 16 + q4 * 4 + r;
      float s = 0.f;
#pragma unroll
      for (int d = 0; d < 16; ++d) s += semb[d] * bpool[d * OW + o];
      ((float*)&biasv[mi])[r] = s;
    }
#pragma unroll
  for (int mi = 0; mi < MT; ++mi)
#pragma unroll
    for (int ni = 0; ni < 4; ++ni) {
      const int b = ni * 16 + cl;
      float4 v;
      v.x = acc[mi][ni][0] + biasv[mi].x;
      v.y = acc[mi][ni][1] + biasv[mi].y;
      v.z = acc[mi][ni][2] + biasv[mi].z;
      v.w = acc[mi][ni][3] + biasv[mi].w;
      *(float4*)(outp + ((size_t)n * 64 + b) * OW + (w * MT + mi) * 16 + q4 * 4) = v;
    }
}

// ---------------------------------------------------------------------------
// two-stage attention mean; A1 has a K-split partial PZ folded in.
template <int C>
__global__ __launch_bounds__(256) void att_reduce(const float* __restrict__ A0,
                                                  const float* __restrict__ A1,
                                                  const float* __restrict__ PZ,
                                                  float* __restrict__ part0,
                                                  float* __restrict__ part1) {
  constexpr int C4 = C / 4;
  constexpr int H = 256 / C4;
  const int chunk = blockIdx.x;
  const int b = blockIdx.y;
  const int tid = threadIdx.x;
  const int c4 = tid % C4, h = tid / C4;
  __shared__ float4 r0[256], r1[256];
  float4 s0 = {0.f, 0.f, 0.f, 0.f}, s1 = {0.f, 0.f, 0.f, 0.f};
  const float4* p0 = (const float4*)(A0 + (size_t)b * C) + c4;
  const float4* p1 = (const float4*)(A1 + (size_t)b * C) + c4;
  const float4* pz = (const float4*)(PZ + (size_t)b * C) + c4;
  const size_t stride = (size_t)B_ * C4;
  for (int n = chunk * 64 + h; n < chunk * 64 + 64; n += H) {
    float4 v0 = p0[(size_t)n * stride];
    float4 v1 = p1[(size_t)n * stride];
    float4 u1 = pz[(size_t)n * stride];
    s0.x += lrelu(v0.x); s0.y += lrelu(v0.y); s0.z += lrelu(v0.z); s0.w += lrelu(v0.w);
    s1.x += lrelu(v1.x + u1.x); s1.y += lrelu(v1.y + u1.y);
    s1.z += lrelu(v1.z + u1.z); s1.w += lrelu(v1.w + u1.w);
  }
  r0[tid] = s0; r1[tid] = s1;
  __syncthreads();
  if (h == 0) {
    for (int hh = 1; hh < H; ++hh) {
      float4 a = r0[c4 + hh * C4], bb = r1[c4 + hh * C4];
      s0.x += a.x; s0.y += a.y; s0.z += a.z; s0.w += a.w;
      s1.x += bb.x; s1.y += bb.y; s1.z += bb.z; s1.w += bb.w;
    }
    ((float4*)(part0 + ((size_t)b * 16 + chunk) * C))[c4] = s0;
    ((float4*)(part1 + ((size_t)b * 16 + chunk) * C))[c4] = s1;
  }
}

template <int C, int HID>
__global__ __launch_bounds__(256) void att_finish(const float* __restrict__ part0,
                                                  const float* __restrict__ part1,
                                                  const float* __restrict__ w11,
                                                  const float* __restrict__ w12,
                                                  const float* __restrict__ w21,
                                                  const float* __restrict__ w22,
                                                  float* __restrict__ sout) {
  const int b = blockIdx.x;
  const int tid = threadIdx.x;
  __shared__ float sm0[C], sm1[C];
  __shared__ float h0[HID], h1[HID];
  if (tid < C) {
    float s0 = 0.f, s1 = 0.f;
    for (int ch = 0; ch < 16; ++ch) {
      s0 += part0[((size_t)b * 16 + ch) * C + tid];
      s1 += part1[((size_t)b * 16 + ch) * C + tid];
    }
    sm0[tid] = s0 * (1.f / N_); sm1[tid] = s1 * (1.f / N_);
  }
  __syncthreads();
  if (tid < HID) {
    float a = 0.f;
    for (int cc = 0; cc < C; ++cc) a += sm0[cc] * w11[tid * C + cc];
    h0[tid] = fmaxf(a, 0.f);
  } else if (tid >= 32 && tid < 32 + HID) {
    int j = tid - 32;
    float a = 0.f;
    for (int cc = 0; cc < C; ++cc) a += sm1[cc] * w21[j * C + cc];
    h1[j] = fmaxf(a, 0.f);
  }
  __syncthreads();
  if (tid == 0) {
    float a = 0.f;
    for (int j = 0; j < HID; ++j) a += h0[j] * w12[j];
    sout[b] = sigmoidf_(a);
  } else if (tid == 32) {
    float a = 0.f;
    for (int j = 0; j < HID; ++j) a += h1[j] * w22[j];
    sout[B_ + b] = sigmoidf_(a);
  }
}

// ---------------------------------------------------------------------------
// gate combine -> cand fp32 + candb bf16 + rbuf fp32 (a1 gets +pz partial)
__global__ __launch_bounds__(256) void gate_combine_b2(const float* __restrict__ a0,
                                                       const float* __restrict__ a1,
                                                       const float* __restrict__ pz,
                                                       const float* __restrict__ s12,
                                                       const float* __restrict__ x,
                                                       const float* __restrict__ st,
                                                       float* __restrict__ cand,
                                                       u16* __restrict__ candb,
                                                       float* __restrict__ rbuf) {
  size_t t = (size_t)blockIdx.x * 256 + threadIdx.x;
  if (t >= (size_t)B_ * N_ * 64) return;
  int c = (int)(t & 63);
  int b = (int)((t >> 6) & 63);
  int n = (int)(t >> 12);
  float s1 = s12[b], s2 = s12[B_ + b];
  size_t nb = (size_t)n * B_ + b;
  size_t i128 = nb * 128;
  float uz = s1 * lrelu(a0[i128 + c]) + s2 * lrelu(a1[i128 + c] + pz[i128 + c]);
  float ur = s1 * lrelu(a0[i128 + 64 + c]) + s2 * lrelu(a1[i128 + 64 + c] + pz[i128 + 64 + c]);
  float z = sigmoidf_(uz);
  float r = sigmoidf_(ur);
  float stv = st[((size_t)b * N_ + n) * 64 + c];
  float zs = z * stv;
  cand[nb * CIN_ + 32 + c] = zs;
  candb[nb * CIN_ + 32 + c] = f2b(zs);
  rbuf[nb * 64 + c] = r;
  if (c < 32) {
    float xv = x[((size_t)b * N_ + n) * 32 + c];
    cand[nb * CIN_ + c] = xv;
    candb[nb * CIN_ + c] = f2b(xv);
  }
}

__global__ __launch_bounds__(256) void final_h(const float* __restrict__ a0,
                                               const float* __restrict__ a1,
                                               const float* __restrict__ pz,
                                               const float* __restrict__ s12,
                                               const float* __restrict__ rbuf,
                                               const float* __restrict__ st,
                                               float* __restrict__ out) {
  size_t t = (size_t)blockIdx.x * 256 + threadIdx.x;
  if (t >= (size_t)B_ * N_ * 64) return;
  int o = (int)(t & 63);
  int n = (int)((t >> 6) & 1023);
  int b = (int)(t >> 16);
  float s1 = s12[b], s2 = s12[B_ + b];
  size_t nb = ((size_t)n * B_ + b) * 64 + o;
  float u = s1 * lrelu(a0[nb]) + s2 * lrelu(a1[nb] + pz[nb]);
  float hc = tanhf(u);
  float r = rbuf[nb];
  out[t] = r * st[t] + (1.f - r) * hc;
}

// ---------------------------------------------------------------------------
extern "C" void kernel_launch(void* const* d_in, const int* in_sizes, int n_in,
                              void* d_out, int out_size, void* d_ws, size_t ws_size,
                              hipStream_t stream) {
  const float* x       = (const float*)d_in[0];
  const float* state   = (const float*)d_in[1];
  const float* emb     = (const float*)d_in[2];
  const float* Ltil    = (const float*)d_in[3];
  const float* cheb    = (const float*)d_in[4];
  const float* g_wpool = (const float*)d_in[5];
  const float* g_bpool = (const float*)d_in[6];
  const float* g_iw    = (const float*)d_in[7];
  const float* g_ib    = (const float*)d_in[8];
  const float* g_gw    = (const float*)d_in[9];
  const float* g_gb    = (const float*)d_in[10];
  const float* g_a1w1  = (const float*)d_in[11];
  const float* g_a1w2  = (const float*)d_in[12];
  const float* g_a2w1  = (const float*)d_in[13];
  const float* g_a2w2  = (const float*)d_in[14];
  const float* u_wpool = (const float*)d_in[15];
  const float* u_bpool = (const float*)d_in[16];
  const float* u_iw    = (const float*)d_in[17];
  const float* u_ib    = (const float*)d_in[18];
  const float* u_gw    = (const float*)d_in[19];
  const float* u_gb    = (const float*)d_in[20];
  const float* u_a1w1  = (const float*)d_in[21];
  const float* u_a1w2  = (const float*)d_in[22];
  const float* u_a2w1  = (const float*)d_in[23];
  const float* u_a2w2  = (const float*)d_in[24];
  float* out = (float*)d_out;

  // workspace (float offsets), ~240.3 MB (same layout as R17).
  // R18: K-split partial Pk lives at t12 start (Zbuf dead by cheb-GEMM time;
  // gate Pk [1024][8192]=8.39M fl, update Pk [1024][4096]=4.19M fl; consumed
  // before the next writer of t12).
  float* ws    = (float*)d_ws;
  float* inp   = ws;                       // [65536][96] fp32 (later cand)
  u16*   inpb  = (u16*)(ws + 6291456);     // [65536][96] bf16 (later candb)
  float* t12   = ws + 9437184;             // [2048][6144] fp32; Zbuf overlays;
                                           //   also L2-partials P[3][1M] at init
  u16*   Zbuf  = (u16*)t12;                //   gate [65536][384] bf16 (exact fit)
  float* Pk    = t12;                      // K-split partial (overlay, dead Zbuf)
  u16*   Wbuf  = (u16*)(ws + 22020096);    // update Wt [1024][64][288] bf16
  u16*   Wbuf128 = Wbuf;                   // gate Wt [1024][128][288] bf16 (overlay)
  u16*   Btp   = (u16*)(ws + 31457280);    // [6144][1024] bf16
  u16*   Zt    = Wbuf;                     // overlay Wbuf+Btp: [24576][1024]
  float* acc1  = ws + 34603008;            // [n,b,128]
  float* acc0  = ws + 42991616;            // [n,b,128]
  u16*   LbStk = (u16*)(ws + 51380224);    // [2048][1024] bf16 (Lhi ; L2)
  u16*   chebb = (u16*)(ws + 52428800);    // [3][1024][1024] bf16
  float* s12   = ws + 54001664;
  float* s12u  = ws + 54001792;
  float* part0 = ws + 54001920;            // [64][16][128]
  float* part1 = ws + 54132992;
  float* rbuf  = ws + 54264064;            // [n,b,64]
  u16*   Vbg   = (u16*)(ws + 58458368);    // [384][96] = 18432 fl
  float* bag   = ws + 58476800;            // [384]
  u16*   Vbu   = (u16*)(ws + 58477184);    // [256][96] = 12288 fl
  float* bau   = ws + 58489472;            // [256]
  u16*   LhiT  = (u16*)(ws + 58489728);    // [1024][1024] bf16
  u16*   LloT  = (u16*)(ws + 59014016);    // [1024][1024] bf16
  u16*   Llo   = (u16*)(ws + 59538304);    // [1024][1024] bf16  (end 60,062,592)
  float* wpTg  = ws + 58489728;            // overlay LhiT+ (dead after l2p)
  float* wpTu  = ws + 59079552;

  dim3 blk(256);
  dim3 blk512(512);

  // ---- init ----
  split_hilo<<<1024, blk, 0, stream>>>(Ltil, LbStk, Llo, 262144);
  transpose_split<<<dim3(32, 32), blk, 0, stream>>>(Ltil, LhiT, LloT);
  mfma_l2p<<<dim3(16, 16, 3), blk, 0, stream>>>(LbStk, Llo, LhiT, LloT, t12);
  wpool_tr<<<dim3(9, 4, 16), blk, 0, stream>>>(g_wpool, wpTg, 128);
  wpool_tr<<<dim3(9, 2, 16), blk, 0, stream>>>(u_wpool, wpTu, 64);
  l2_finish<<<1024, blk, 0, stream>>>(t12, LbStk + 1048576);
  conv_f2b<<<3072, blk, 0, stream>>>(cheb, chebb, 786432);

  // ---- gate AVWGCN (dim_out = 128) ----
  concat_bf2<<<24576, blk, 0, stream>>>(x, state, inp, inpb);
  transpose_b2b<<<dim3(3, 32, 64), blk, 0, stream>>>(inpb, 96, 96, Btp);
  mfma_stack_w<<<dim3(24, 16), blk512, 0, stream>>>(LbStk, Btp, t12, 6144);
  vgen2<128, 7><<<384, dim3(128), 0, stream>>>(g_gw, g_iw, g_ib, 384, Vbg, bag);
  weightgen5<36864><<<dim3(144, 16), blk, 0, stream>>>(emb, wpTg, Wbuf128);
  pernode10<128><<<1024, blk, 0, stream>>>(inp, t12, Wbuf128, emb, g_bpool, acc0);
  zgemm<<<dim3(3, 512), blk, 0, stream>>>(inpb, Vbg, bag, Zbuf, 384);   // overlays t12 (dead)
  transpose_b2b<<<dim3(12, 32, 64), blk, 0, stream>>>(Zbuf, 384, 384, Zt);  // kills Wbuf/Btp
  mfma_k3ws<<<dim3(32, 8, 2), blk512, 0, stream>>>(chebb, Zt, g_gb, acc1, Pk, 8192, 7);
  att_reduce<128><<<dim3(16, 64), blk, 0, stream>>>(acc0, acc1, Pk, part0, part1);
  att_finish<128, 8><<<64, blk, 0, stream>>>(part0, part1, g_a1w1, g_a1w2, g_a2w1, g_a2w2, s12);
  gate_combine_b2<<<16384, blk, 0, stream>>>(acc0, acc1, Pk, s12, x, state, inp, inpb, rbuf);

  // ---- update AVWGCN (dim_out = 64), input = cand/candb ----
  transpose_b2b<<<dim3(3, 32, 64), blk, 0, stream>>>(inpb, 96, 96, Btp);
  mfma_stack_w<<<dim3(24, 16), blk512, 0, stream>>>(LbStk, Btp, t12, 6144);
  vgen2<64, 6><<<256, dim3(128), 0, stream>>>(u_gw, u_iw, u_ib, 192, Vbu, bau);
  weightgen5<18432><<<dim3(72, 16), blk, 0, stream>>>(emb, wpTu, Wbuf);
  pernode10<64><<<1024, blk, 0, stream>>>(inp, t12, Wbuf, emb, u_bpool, acc0);
  zgemm<<<dim3(2, 512), blk, 0, stream>>>(inpb, Vbu, bau, Zbuf, 256);
  transpose_b2b<<<dim3(6, 32, 64), blk, 0, stream>>>(Zbuf, 256, 192, Zt);
  mfma_k3s<<<dim3(32, 8, 2), blk512, 0, stream>>>(chebb, Zt, u_gb, acc1, Pk, 4096, 6);
  att_reduce<64><<<dim3(16, 64), blk, 0, stream>>>(acc0, acc1, Pk, part0, part1);
  att_finish<64, 4><<<64, blk, 0, stream>>>(part0, part1, u_a1w1, u_a1w2, u_a2w1, u_a2w2, s12u);
  final_h<<<16384, blk, 0, stream>>>(acc0, acc1, Pk, s12u, rbuf, state, out);
}

// Round 11
// 632.855 us; speedup vs baseline: 1.0126x; 1.0126x over previous
//
#include <hip/hip_runtime.h>
#include <hip/hip_bf16.h>
#include <math.h>

// RGSLCell on MI355X. R19 = R17 with the gate cheb GEMM reverted to the
// R11-PROVEN kernel (A/B closure):
//  R18's K-split doubled occupancy but introduced 6.29M bank conflicts
//  (BK=32 swizzle used r&3 where 64B rows need (r>>1)&3) + 3x write traffic
//  -> regressed. R11 already measured the gate as mfma_k3 128x128/8-wave/
//  BK=64 at grid (64,8) = 2 blocks/CU, 0 conflicts: 58.2us. R12 switched to
//  the 1-block/CU k3w (63.5us in R17) without an A/B - hidden regression.
//  R19: gate = mfma_k3 (64,8); update = mfma_k3 (32,8); no K-split, no Pk.
//  Same ascending per-output K-chain -> bit-identical to R17.
// Everything else identical to R17 (631.2us, absmax 0.078125).

#define B_  64
#define N_  1024
#define CIN_ 96
#define R_  288

typedef __attribute__((ext_vector_type(8))) short bf16x8;
typedef __attribute__((ext_vector_type(4))) float f32x4;
typedef unsigned short u16;
typedef unsigned int u32;

__device__ __forceinline__ float lrelu(float v) { return v >= 0.f ? v : 0.01f * v; }
__device__ __forceinline__ float sigmoidf_(float u) { return 1.f / (1.f + expf(-u)); }
// round-to-nearest-even fp32 -> bf16
__device__ __forceinline__ u16 f2b(float f) {
  union { float f; u32 u; } c; c.f = f;
  u32 u = c.u;
  return (u16)((u + 0x7FFFu + ((u >> 16) & 1u)) >> 16);
}
__device__ __forceinline__ float b2f(u16 u) {
  union { u32 x; float f; } c; c.x = ((u32)u) << 16; return c.f;
}
__device__ __forceinline__ void gload_lds16(const u16* gp, u16* lp) {
  __builtin_amdgcn_global_load_lds((const __attribute__((address_space(1))) u32*)gp,
                                   (__attribute__((address_space(3))) u32*)lp, 16, 0, 0);
}

// ---------------------------------------------------------------------------
// concat: inp fp32 AND inpb bf16, layout [(n*64+b)][96]
__global__ __launch_bounds__(256) void concat_bf2(const float* __restrict__ x,
                                                  const float* __restrict__ st,
                                                  float* __restrict__ inp,
                                                  u16* __restrict__ inpb) {
  size_t t = (size_t)blockIdx.x * 256 + threadIdx.x;
  if (t >= (size_t)B_ * N_ * CIN_) return;
  int i = (int)(t % CIN_);
  size_t v = t / CIN_;
  size_t b = v & 63, n = v >> 6;
  float f = (i < 32) ? x[(b * N_ + n) * 32 + i] : st[(b * N_ + n) * 64 + (i - 32)];
  inp[t] = f;
  inpb[t] = f2b(f);
}

// fp32 -> bf16 flat convert (cheb)
__global__ __launch_bounds__(256) void conv_f2b(const float* __restrict__ in,
                                                u16* __restrict__ out, int n4) {
  int t = blockIdx.x * 256 + threadIdx.x;
  if (t >= n4) return;
  float4 v = ((const float4*)in)[t];
  ushort4 o;
  o.x = f2b(v.x); o.y = f2b(v.y); o.z = f2b(v.z); o.w = f2b(v.w);
  ((ushort4*)out)[t] = o;
}

// split fp32 -> (hi, lo) bf16 planes
__global__ __launch_bounds__(256) void split_hilo(const float* __restrict__ in,
                                                  u16* __restrict__ hi,
                                                  u16* __restrict__ lo, int n4) {
  int t = blockIdx.x * 256 + threadIdx.x;
  if (t >= n4) return;
  float4 v = ((const float4*)in)[t];
  ushort4 h, l;
  h.x = f2b(v.x); l.x = f2b(v.x - b2f(h.x));
  h.y = f2b(v.y); l.y = f2b(v.y - b2f(h.y));
  h.z = f2b(v.z); l.z = f2b(v.z - b2f(h.z));
  h.w = f2b(v.w); l.w = f2b(v.w - b2f(h.w));
  ((ushort4*)hi)[t] = h;
  ((ushort4*)lo)[t] = l;
}

// transpose fp32 [1024][1024] -> (hiT, loT) bf16 planes of L^T
__global__ __launch_bounds__(256) void transpose_split(const float* __restrict__ in,
                                                       u16* __restrict__ hiT,
                                                       u16* __restrict__ loT) {
  __shared__ float t[32][33];
  const int tid = threadIdx.x;
  const int j0 = blockIdx.x * 32, r0 = blockIdx.y * 32;
  const int tc = tid & 31, tr = tid >> 5;
#pragma unroll
  for (int q = 0; q < 4; ++q)
    t[tr + q * 8][tc] = in[(size_t)(r0 + tr + q * 8) * 1024 + j0 + tc];
  __syncthreads();
  const int jj = tid >> 3, rq = (tid & 7) * 4;
  ushort4 h, l;
#pragma unroll
  for (int q = 0; q < 4; ++q) {
    float v = t[rq + q][jj];
    u16 hh = f2b(v);
    ((u16*)&h)[q] = hh;
    ((u16*)&l)[q] = f2b(v - b2f(hh));
  }
  *(ushort4*)(hiT + (size_t)(j0 + jj) * N_ + r0 + rq) = h;
  *(ushort4*)(loT + (size_t)(j0 + jj) * N_ + r0 + rq) = l;
}

// transpose bf16 [(n*64+b)][Zs] -> bf16 [(b*Ctot+c)][1024]
__global__ __launch_bounds__(256) void transpose_b2b(const u16* __restrict__ Z, int Zs,
                                                     int Ctot, u16* __restrict__ Zt) {
  __shared__ u16 t[32][36];
  const int tid = threadIdx.x;
  const int c0 = blockIdx.x * 32, n0 = blockIdx.y * 32, b = blockIdx.z;
  {
    const int i = tid >> 3, c4 = (tid & 7) * 4;
    ushort4 v = *(const ushort4*)(Z + ((size_t)(n0 + i) * 64 + b) * Zs + c0 + c4);
    t[i][c4] = v.x; t[i][c4 + 1] = v.y; t[i][c4 + 2] = v.z; t[i][c4 + 3] = v.w;
  }
  __syncthreads();
  {
    const int c = tid >> 3, n4 = (tid & 7) * 4;
    ushort4 o;
    o.x = t[n4][c]; o.y = t[n4 + 1][c]; o.z = t[n4 + 2][c]; o.w = t[n4 + 3][c];
    *(ushort4*)(Zt + (size_t)(b * Ctot + c0 + c) * 1024 + n0 + n4) = o;
  }
}

// wpool transpose: wpT[d][o][r] = wp[d][r][o]. grid (288/32, OW/32, 16).
__global__ __launch_bounds__(256) void wpool_tr(const float* __restrict__ wp,
                                                float* __restrict__ wpT, int OW) {
  __shared__ float t[32][33];
  const int tid = threadIdx.x;
  const int r0 = blockIdx.x * 32, o0 = blockIdx.y * 32, d = blockIdx.z;
  const size_t base = (size_t)d * 288 * OW;
  const int c = tid & 31, q0 = tid >> 5;
#pragma unroll
  for (int q = 0; q < 4; ++q)
    t[q0 + q * 8][c] = wp[base + (size_t)(r0 + q0 + q * 8) * OW + o0 + c];
  __syncthreads();
#pragma unroll
  for (int q = 0; q < 4; ++q)
    wpT[base + (size_t)(o0 + q0 + q * 8) * 288 + r0 + c] = t[c][q0 + q * 8];
}

// ---------------------------------------------------------------------------
// compensated L2, phase-split: P[z] = (z==0 ? Lhi@Lhi : z==1 ? Llo@Lhi : Lhi@Llo)
__global__ __launch_bounds__(256) void mfma_l2p(const u16* __restrict__ Lhi,
                                                const u16* __restrict__ Llo,
                                                const u16* __restrict__ LhiT,
                                                const u16* __restrict__ LloT,
                                                float* __restrict__ P) {
  __shared__ u16 Asl[64 * 64];
  __shared__ u16 Bsl[64 * 64];
  const int tid = threadIdx.x;
  const int w = tid >> 6, lane = tid & 63;
  const int m0 = blockIdx.y * 64, n0 = blockIdx.x * 64;
  const int ph = blockIdx.z;
  const int wr = w >> 1, wc = w & 1;
  const int sr = lane >> 3, so = lane & 7;
  const int cl = lane & 15, q4 = lane >> 4;
  f32x4 acc[2][2] = {};

  const u16* A = (ph == 1) ? Llo : Lhi;
  const u16* B = (ph == 2) ? LloT : LhiT;
  for (int k0 = 0; k0 < 1024; k0 += 64) {
    __syncthreads();
#pragma unroll
    for (int i = 0; i < 2; ++i) {
      const int r = i * 32 + w * 8 + sr;
      const int o = so ^ (r & 7);
      gload_lds16(A + (size_t)(m0 + r) * 1024 + k0 + o * 8, Asl + (i * 32 + w * 8) * 64);
      gload_lds16(B + (size_t)(n0 + r) * 1024 + k0 + o * 8, Bsl + (i * 32 + w * 8) * 64);
    }
    __syncthreads();
#pragma unroll
    for (int kk = 0; kk < 2; ++kk) {
      bf16x8 af[2], bfr[2];
#pragma unroll
      for (int mi = 0; mi < 2; ++mi) {
        const int ra = wr * 32 + mi * 16 + cl;
        af[mi] = *(const bf16x8*)(Asl + ra * 64 + ((kk * 4 + q4) ^ (ra & 7)) * 8);
      }
#pragma unroll
      for (int ni = 0; ni < 2; ++ni) {
        const int rb = wc * 32 + ni * 16 + cl;
        bfr[ni] = *(const bf16x8*)(Bsl + rb * 64 + ((kk * 4 + q4) ^ (rb & 7)) * 8);
      }
#pragma unroll
      for (int mi = 0; mi < 2; ++mi)
#pragma unroll
        for (int ni = 0; ni < 2; ++ni)
          acc[mi][ni] = __builtin_amdgcn_mfma_f32_16x16x32_bf16(af[mi], bfr[ni], acc[mi][ni], 0, 0, 0);
    }
  }
  float* Pz = P + ((size_t)ph << 20);
#pragma unroll
  for (int mi = 0; mi < 2; ++mi)
#pragma unroll
    for (int ni = 0; ni < 2; ++ni) {
      const int j = n0 + wc * 32 + ni * 16 + cl;
#pragma unroll
      for (int r = 0; r < 4; ++r) {
        const int m = m0 + wr * 32 + mi * 16 + q4 * 4 + r;
        Pz[(size_t)m * 1024 + j] = acc[mi][ni][r];
      }
    }
}

// combine the 3 partials: Y = bf16(2*(P0+P1+P2) - I)
__global__ __launch_bounds__(256) void l2_finish(const float* __restrict__ P,
                                                 u16* __restrict__ Y) {
  int t = blockIdx.x * 256 + threadIdx.x;   // 262144 float4 groups
  float4 a = ((const float4*)P)[t];
  float4 b = ((const float4*)(P + 1048576))[t];
  float4 c = ((const float4*)(P + 2097152))[t];
  int e = t << 2;
  int m = e >> 10, j = e & 1023;
  ushort4 o;
  o.x = f2b(2.f * (a.x + b.x + c.x) - (m == j     ? 1.f : 0.f));
  o.y = f2b(2.f * (a.y + b.y + c.y) - (m == j + 1 ? 1.f : 0.f));
  o.z = f2b(2.f * (a.z + b.z + c.z) - (m == j + 2 ? 1.f : 0.f));
  o.w = f2b(2.f * (a.w + b.w + c.w) - (m == j + 3 ? 1.f : 0.f));
  ((ushort4*)Y)[t] = o;
}

// ---------------------------------------------------------------------------
// wide-tile stack GEMM: Y[2048][J] = A@B, A bf16 [2048][1024], Bt bf16 [J][1024].
// 128(M)x256(N), 8 waves 2x2, 64x64/wave acc[4][4]. LDS 96 KB, vmcnt(6).
__global__ __launch_bounds__(512) void mfma_stack_w(const u16* __restrict__ A,
                                                    const u16* __restrict__ Bt,
                                                    float* __restrict__ Y, int J) {
  __shared__ u16 Asl[2][128 * 64];
  __shared__ u16 Bsl[2][256 * 64];
  const int tid = threadIdx.x;
  const int w = tid >> 6, lane = tid & 63;    // w 0..7
  const int m0 = blockIdx.y * 128, n0 = blockIdx.x * 256;
  const int wr = w >> 2, wc = w & 3;          // wr 0..1 (64-row), wc 0..3 (64-col)
  const int sr = lane >> 3, so = lane & 7;
  const int cl = lane & 15, q4 = lane >> 4;
  f32x4 acc[4][4] = {};

  auto STAGE = [&](u16* Ad, u16* Bd, int k0) {
#pragma unroll
    for (int i = 0; i < 2; ++i) {
      const int r = i * 64 + w * 8 + sr;
      const int o = so ^ (r & 7);
      gload_lds16(A + (size_t)(m0 + r) * 1024 + k0 + o * 8, Ad + (i * 64 + w * 8) * 64);
    }
#pragma unroll
    for (int i = 0; i < 4; ++i) {
      const int r = i * 64 + w * 8 + sr;
      const int o = so ^ (r & 7);
      gload_lds16(Bt + (size_t)(n0 + r) * 1024 + k0 + o * 8, Bd + (i * 64 + w * 8) * 64);
    }
  };
  auto COMPUTE = [&](const u16* As, const u16* Bs) {
#pragma unroll
    for (int kk = 0; kk < 2; ++kk) {
      bf16x8 af[4], bfr[4];
#pragma unroll
      for (int mi = 0; mi < 4; ++mi) {
        const int ra = wr * 64 + mi * 16 + cl;
        af[mi] = *(const bf16x8*)(As + ra * 64 + ((kk * 4 + q4) ^ (ra & 7)) * 8);
      }
#pragma unroll
      for (int ni = 0; ni < 4; ++ni) {
        const int rb = wc * 64 + ni * 16 + cl;
        bfr[ni] = *(const bf16x8*)(Bs + rb * 64 + ((kk * 4 + q4) ^ (rb & 7)) * 8);
      }
#pragma unroll
      for (int mi = 0; mi < 4; ++mi)
#pragma unroll
        for (int ni = 0; ni < 4; ++ni)
          acc[mi][ni] = __builtin_amdgcn_mfma_f32_16x16x32_bf16(af[mi], bfr[ni], acc[mi][ni], 0, 0, 0);
    }
  };

  STAGE(Asl[0], Bsl[0], 0);
  for (int k0 = 0; k0 < 1024; k0 += 128) {
    STAGE(Asl[1], Bsl[1], k0 + 64);
    asm volatile("s_waitcnt vmcnt(6)" ::: "memory");
    __builtin_amdgcn_s_barrier();
    __builtin_amdgcn_sched_barrier(0);
    COMPUTE(Asl[0], Bsl[0]);
    asm volatile("s_waitcnt lgkmcnt(0)" ::: "memory");
    __builtin_amdgcn_s_barrier();
    __builtin_amdgcn_sched_barrier(0);
    if (k0 + 128 < 1024) {
      STAGE(Asl[0], Bsl[0], k0 + 128);
      asm volatile("s_waitcnt vmcnt(6)" ::: "memory");
    } else {
      asm volatile("s_waitcnt vmcnt(0)" ::: "memory");
    }
    __builtin_amdgcn_s_barrier();
    __builtin_amdgcn_sched_barrier(0);
    COMPUTE(Asl[1], Bsl[1]);
    asm volatile("s_waitcnt lgkmcnt(0)" ::: "memory");
    __builtin_amdgcn_s_barrier();
    __builtin_amdgcn_sched_barrier(0);
  }
#pragma unroll
  for (int mi = 0; mi < 4; ++mi)
#pragma unroll
    for (int ni = 0; ni < 4; ++ni) {
      const int j = n0 + wc * 64 + ni * 16 + cl;
#pragma unroll
      for (int r = 0; r < 4; ++r) {
        const int m = m0 + wr * 64 + mi * 16 + q4 * 4 + r;
        Y[(size_t)m * J + j] = acc[mi][ni][r];
      }
    }
}

// ---------------------------------------------------------------------------
// vgen2: one block per output row c.
template <int O, int OSH>
__global__ __launch_bounds__(128) void vgen2(const float* __restrict__ gw,
                                             const float* __restrict__ iw,
                                             const float* __restrict__ ib,
                                             int Ctot,
                                             u16* __restrict__ Vb,
                                             float* __restrict__ ball) {
  const int c = blockIdx.x;
  const int col = threadIdx.x;
  if (c >= Ctot) {  // zero-pad (block-uniform branch)
    if (col < 96) Vb[(size_t)c * 96 + col] = 0;
    else if (col == 96) ball[c] = 0.f;
    return;
  }
  __shared__ float sg[O];
  const int o = c & (O - 1), k = c >> OSH;
  const float* g = gw + (size_t)o * (3 * O) + (size_t)k * O;
  for (int e = col; e < O; e += 128) sg[e] = g[e];
  __syncthreads();
  if (col < 96) {
    float s = 0.f;
#pragma unroll
    for (int j = 0; j < O; ++j) s += sg[j] * iw[j * 96 + col];
    Vb[(size_t)c * 96 + col] = f2b(s);
  } else if (col == 96) {
    float s = 0.f;
#pragma unroll
    for (int j = 0; j < O; ++j) s += sg[j] * ib[j];
    ball[c] = s;
  }
}

// ---------------------------------------------------------------------------
// zgemm: Z[M][Zs] bf16 = A[M][96] @ Vb^T + ball. 128x128 tile, BK=32 x 3.
__global__ __launch_bounds__(256) void zgemm(const u16* __restrict__ A,
                                             const u16* __restrict__ Bt,
                                             const float* __restrict__ ball,
                                             u16* __restrict__ Z, int Zs) {
  __shared__ u16 Asl[128 * 32];
  __shared__ u16 Bsl[128 * 32];
  const int tid = threadIdx.x;
  const int w = tid >> 6, lane = tid & 63;
  const int m0 = blockIdx.y * 128, n0 = blockIdx.x * 128;
  const int wr = w >> 1, wc = w & 1;
  const int sr = lane >> 2, so = lane & 3;
  const int cl = lane & 15, q4 = lane >> 4;
  f32x4 acc[4][4] = {};
  for (int k0 = 0; k0 < 96; k0 += 32) {
    __syncthreads();
#pragma unroll
    for (int i = 0; i < 2; ++i) {
      const int r = i * 64 + w * 16 + sr;
      const int o = so ^ (r & 3);
      gload_lds16(A + (size_t)(m0 + r) * 96 + k0 + o * 8, Asl + (i * 64 + w * 16) * 32);
      gload_lds16(Bt + (size_t)(n0 + r) * 96 + k0 + o * 8, Bsl + (i * 64 + w * 16) * 32);
    }
    __syncthreads();
    bf16x8 af[4], bfr[4];
#pragma unroll
    for (int mi = 0; mi < 4; ++mi) {
      const int ra = wr * 64 + mi * 16 + cl;
      af[mi] = *(const bf16x8*)(Asl + ra * 32 + (q4 ^ (ra & 3)) * 8);
    }
#pragma unroll
    for (int ni = 0; ni < 4; ++ni) {
      const int rb = wc * 64 + ni * 16 + cl;
      bfr[ni] = *(const bf16x8*)(Bsl + rb * 32 + (q4 ^ (rb & 3)) * 8);
    }
#pragma unroll
    for (int mi = 0; mi < 4; ++mi)
#pragma unroll
      for (int ni = 0; ni < 4; ++ni)
        acc[mi][ni] = __builtin_amdgcn_mfma_f32_16x16x32_bf16(af[mi], bfr[ni], acc[mi][ni], 0, 0, 0);
  }
#pragma unroll
  for (int mi = 0; mi < 4; ++mi)
#pragma unroll
    for (int ni = 0; ni < 4; ++ni) {
      const int c = n0 + wc * 64 + ni * 16 + cl;
      const float bb = ball[c];
#pragma unroll
      for (int r = 0; r < 4; ++r) {
        const int m = m0 + wr * 64 + mi * 16 + q4 * 4 + r;
        Z[(size_t)m * Zs + c] = f2b(acc[mi][ni][r] + bb);
      }
    }
}

// ---------------------------------------------------------------------------
// stacked-K cheb GEMM, 128x128, 8 waves (2x4), acc[4][2], BK=64, 64KB LDS.
// GATE: grid (64,8) = 512 blocks = 2 blocks/CU (R11-proven 58us).
// UPDATE: grid (32,8) = 256 blocks.
__global__ __launch_bounds__(512) void mfma_k3(const u16* __restrict__ A3,
                                               const u16* __restrict__ Zt,
                                               const float* __restrict__ gb,
                                               float* __restrict__ Y,
                                               int J, int obits) {
  __shared__ u16 Asl[2][128 * 64];
  __shared__ u16 Bsl[2][128 * 64];
  const int tid = threadIdx.x;
  const int w = tid >> 6, lane = tid & 63;    // w 0..7
  const int m0 = blockIdx.y * 128, n0 = blockIdx.x * 128;
  const int wr = w >> 2, wc = w & 3;          // wr 0..1, wc 0..3
  const int sr = lane >> 3, so = lane & 7;
  const int cl = lane & 15, q4 = lane >> 4;
  const int omask = (1 << obits) - 1;
  f32x4 acc[4][2] = {};

  auto STAGE = [&](u16* Ad, u16* Bd, int k0) {
    const int kb = k0 >> 10, ko = k0 & 1023;
#pragma unroll
    for (int i = 0; i < 2; ++i) {
      const int r = i * 64 + w * 8 + sr;
      const int o = so ^ (r & 7);
      gload_lds16(A3 + (size_t)kb * 1048576 + (size_t)(m0 + r) * 1024 + ko + o * 8,
                  Ad + (i * 64 + w * 8) * 64);
      const int jp = n0 + r;
      const int brow = (((jp >> obits) * 3 + kb) << obits) | (jp & omask);
      gload_lds16(Zt + (size_t)brow * 1024 + ko + o * 8, Bd + (i * 64 + w * 8) * 64);
    }
  };
  auto COMPUTE = [&](const u16* As, const u16* Bs) {
#pragma unroll
    for (int kk = 0; kk < 2; ++kk) {
      bf16x8 af[4], bfr[2];
#pragma unroll
      for (int mi = 0; mi < 4; ++mi) {
        const int ra = wr * 64 + mi * 16 + cl;
        af[mi] = *(const bf16x8*)(As + ra * 64 + ((kk * 4 + q4) ^ (ra & 7)) * 8);
      }
#pragma unroll
      for (int ni = 0; ni < 2; ++ni) {
        const int rb = wc * 32 + ni * 16 + cl;
        bfr[ni] = *(const bf16x8*)(Bs + rb * 64 + ((kk * 4 + q4) ^ (rb & 7)) * 8);
      }
#pragma unroll
      for (int mi = 0; mi < 4; ++mi)
#pragma unroll
        for (int ni = 0; ni < 2; ++ni)
          acc[mi][ni] = __builtin_amdgcn_mfma_f32_16x16x32_bf16(af[mi], bfr[ni], acc[mi][ni], 0, 0, 0);
    }
  };

  STAGE(Asl[0], Bsl[0], 0);
  for (int k0 = 0; k0 < 3072; k0 += 128) {
    STAGE(Asl[1], Bsl[1], k0 + 64);
    asm volatile("s_waitcnt vmcnt(4)" ::: "memory");
    __builtin_amdgcn_s_barrier();
    __builtin_amdgcn_sched_barrier(0);
    COMPUTE(Asl[0], Bsl[0]);
    asm volatile("s_waitcnt lgkmcnt(0)" ::: "memory");
    __builtin_amdgcn_s_barrier();
    __builtin_amdgcn_sched_barrier(0);
    if (k0 + 128 < 3072) {
      STAGE(Asl[0], Bsl[0], k0 + 128);
      asm volatile("s_waitcnt vmcnt(4)" ::: "memory");
    } else {
      asm volatile("s_waitcnt vmcnt(0)" ::: "memory");
    }
    __builtin_amdgcn_s_barrier();
    __builtin_amdgcn_sched_barrier(0);
    COMPUTE(Asl[1], Bsl[1]);
    asm volatile("s_waitcnt lgkmcnt(0)" ::: "memory");
    __builtin_amdgcn_s_barrier();
    __builtin_amdgcn_sched_barrier(0);
  }
#pragma unroll
  for (int mi = 0; mi < 4; ++mi)
#pragma unroll
    for (int ni = 0; ni < 2; ++ni) {
      const int j = n0 + wc * 32 + ni * 16 + cl;
      const float bb = gb[j & omask];
#pragma unroll
      for (int r = 0; r < 4; ++r) {
        const int m = m0 + wr * 64 + mi * 16 + q4 * 4 + r;
        Y[(size_t)m * J + j] = acc[mi][ni][r] + bb;
      }
    }
}

// ---------------------------------------------------------------------------
// weightgen5: Wt[n][SZ] bf16 = sum_d emb[n][d]*wpoolT[d][SZ] (linear; SZ=OW*288)
template <int SZ>
__global__ __launch_bounds__(256) void weightgen5(const float* __restrict__ emb,
                                                  const float* __restrict__ wpT,
                                                  u16* __restrict__ W) {
  const int tid = threadIdx.x;
  const int ro = blockIdx.x * 256 + tid;
  const int n0 = blockIdx.y * 64;
  __shared__ float semb[64][17];
  for (int e = tid; e < 1024; e += 256) semb[e >> 4][e & 15] = emb[(n0 + (e >> 4)) * 16 + (e & 15)];
  __syncthreads();
  float wv[16];
#pragma unroll
  for (int d = 0; d < 16; ++d) wv[d] = wpT[(size_t)d * SZ + ro];
#pragma unroll 4
  for (int n = 0; n < 64; ++n) {
    float s = 0.f;
#pragma unroll
    for (int d = 0; d < 16; ++d) s += semb[n][d] * wv[d];
    W[(size_t)(n0 + n) * SZ + ro] = f2b(s);
  }
}

// pernode10: per-node GEMM on the MATRIX pipe. Block per node, 4 waves.
// C[o][b] = Wt[n] @ X^T. X fp32 -> hi/lo bf16 in LDS. 9 chunks x {hi,lo}.
template <int OW>
__global__ __launch_bounds__(256) void pernode10(const float* __restrict__ xa,
                                                 const float* __restrict__ xbc,
                                                 const u16* __restrict__ Wt,
                                                 const float* __restrict__ emb,
                                                 const float* __restrict__ bpool,
                                                 float* __restrict__ outp) {
  constexpr int MT = OW / 64;            // o 16-tiles per wave (2 gate, 1 upd)
  const int n = blockIdx.x;
  const int tid = threadIdx.x;
  const int w = tid >> 6, lane = tid & 63;
  const int cl = lane & 15, q4 = lane >> 4;
  __shared__ u16 sWt[OW * 32];
  __shared__ u16 sXh[64 * 32];
  __shared__ u16 sXl[64 * 32];
  __shared__ float semb[16];
  if (tid < 16) semb[tid] = emb[n * 16 + tid];
  f32x4 acc[MT][4] = {};
  const u16* Wn = Wt + (size_t)n * (OW * 288);
  const int xb = tid >> 2, rg = tid & 3;  // X staging map: b row, 8-r group

  for (int c = 0; c < 9; ++c) {
    const int k = c / 3, i0 = (c % 3) * 32;
    const float* xk = (k == 0) ? (xa + (size_t)n * 6144)
                               : (xbc + ((size_t)(k - 1) * 1024 + n) * 6144);
    __syncthreads();
#pragma unroll
    for (int i = 0; i < MT; ++i) {
      const int g = w * MT + i;                  // 16-row group
      const int o = g * 16 + (lane >> 2);
      const int seg = (lane & 3) ^ (o & 3);
      gload_lds16(Wn + (size_t)o * 288 + c * 32 + seg * 8, sWt + g * 512);
    }
    {
      const float* p = xk + (size_t)xb * 96 + i0 + rg * 8;
      float4 v0 = *(const float4*)p;
      float4 v1 = *(const float4*)(p + 4);
      float xv[8] = {v0.x, v0.y, v0.z, v0.w, v1.x, v1.y, v1.z, v1.w};
      bf16x8 h, l;
#pragma unroll
      for (int j = 0; j < 8; ++j) {
        u16 hh = f2b(xv[j]);
        ((u16*)&h)[j] = hh;
        ((u16*)&l)[j] = f2b(xv[j] - b2f(hh));
      }
      const int col = (rg ^ (xb & 3)) * 8;
      *(bf16x8*)(sXh + xb * 32 + col) = h;
      *(bf16x8*)(sXl + xb * 32 + col) = l;
    }
    __syncthreads();
    bf16x8 aw[MT], bh[4], bl[4];
#pragma unroll
    for (int mi = 0; mi < MT; ++mi) {
      const int o = (w * MT + mi) * 16 + cl;
      aw[mi] = *(const bf16x8*)(sWt + o * 32 + ((q4 ^ (o & 3)) * 8));
    }
#pragma unroll
    for (int ni = 0; ni < 4; ++ni) {
      const int b = ni * 16 + cl;
      const int col = (q4 ^ (b & 3)) * 8;
      bh[ni] = *(const bf16x8*)(sXh + b * 32 + col);
      bl[ni] = *(const bf16x8*)(sXl + b * 32 + col);
    }
#pragma unroll
    for (int mi = 0; mi < MT; ++mi)
#pragma unroll
      for (int ni = 0; ni < 4; ++ni)
        acc[mi][ni] = __builtin_amdgcn_mfma_f32_16x16x32_bf16(aw[mi], bh[ni], acc[mi][ni], 0, 0, 0);
#pragma unroll
    for (int mi = 0; mi < MT; ++mi)
#pragma unroll
      for (int ni = 0; ni < 4; ++ni)
        acc[mi][ni] = __builtin_amdgcn_mfma_f32_16x16x32_bf16(aw[mi], bl[ni], acc[mi][ni], 0, 0, 0);
  }
  float4 biasv[MT];
#pragma unroll
  for (int mi = 0; mi < MT; ++mi)
#pragma unroll
    for (int r = 0; r < 4; ++r) {
      const int o = (w * MT + mi) * 16 + q4 * 4 + r;
      float s = 0.f;
#pragma unroll
      for (int d = 0; d < 16; ++d) s += semb[d] * bpool[d * OW + o];
      ((float*)&biasv[mi])[r] = s;
    }
#pragma unroll
  for (int mi = 0; mi < MT; ++mi)
#pragma unroll
    for (int ni = 0; ni < 4; ++ni) {
      const int b = ni * 16 + cl;
      float4 v;
      v.x = acc[mi][ni][0] + biasv[mi].x;
      v.y = acc[mi][ni][1] + biasv[mi].y;
      v.z = acc[mi][ni][2] + biasv[mi].z;
      v.w = acc[mi][ni][3] + biasv[mi].w;
      *(float4*)(outp + ((size_t)n * 64 + b) * OW + (w * MT + mi) * 16 + q4 * 4) = v;
    }
}

// ---------------------------------------------------------------------------
// two-stage attention mean
template <int C>
__global__ __launch_bounds__(256) void att_reduce(const float* __restrict__ A0,
                                                  const float* __restrict__ A1,
                                                  float* __restrict__ part0,
                                                  float* __restrict__ part1) {
  constexpr int C4 = C / 4;
  constexpr int H = 256 / C4;
  const int chunk = blockIdx.x;
  const int b = blockIdx.y;
  const int tid = threadIdx.x;
  const int c4 = tid % C4, h = tid / C4;
  __shared__ float4 r0[256], r1[256];
  float4 s0 = {0.f, 0.f, 0.f, 0.f}, s1 = {0.f, 0.f, 0.f, 0.f};
  const float4* p0 = (const float4*)(A0 + (size_t)b * C) + c4;
  const float4* p1 = (const float4*)(A1 + (size_t)b * C) + c4;
  const size_t stride = (size_t)B_ * C4;
  for (int n = chunk * 64 + h; n < chunk * 64 + 64; n += H) {
    float4 v0 = p0[(size_t)n * stride];
    float4 v1 = p1[(size_t)n * stride];
    s0.x += lrelu(v0.x); s0.y += lrelu(v0.y); s0.z += lrelu(v0.z); s0.w += lrelu(v0.w);
    s1.x += lrelu(v1.x); s1.y += lrelu(v1.y); s1.z += lrelu(v1.z); s1.w += lrelu(v1.w);
  }
  r0[tid] = s0; r1[tid] = s1;
  __syncthreads();
  if (h == 0) {
    for (int hh = 1; hh < H; ++hh) {
      float4 a = r0[c4 + hh * C4], bb = r1[c4 + hh * C4];
      s0.x += a.x; s0.y += a.y; s0.z += a.z; s0.w += a.w;
      s1.x += bb.x; s1.y += bb.y; s1.z += bb.z; s1.w += bb.w;
    }
    ((float4*)(part0 + ((size_t)b * 16 + chunk) * C))[c4] = s0;
    ((float4*)(part1 + ((size_t)b * 16 + chunk) * C))[c4] = s1;
  }
}

template <int C, int HID>
__global__ __launch_bounds__(256) void att_finish(const float* __restrict__ part0,
                                                  const float* __restrict__ part1,
                                                  const float* __restrict__ w11,
                                                  const float* __restrict__ w12,
                                                  const float* __restrict__ w21,
                                                  const float* __restrict__ w22,
                                                  float* __restrict__ sout) {
  const int b = blockIdx.x;
  const int tid = threadIdx.x;
  __shared__ float sm0[C], sm1[C];
  __shared__ float h0[HID], h1[HID];
  if (tid < C) {
    float s0 = 0.f, s1 = 0.f;
    for (int ch = 0; ch < 16; ++ch) {
      s0 += part0[((size_t)b * 16 + ch) * C + tid];
      s1 += part1[((size_t)b * 16 + ch) * C + tid];
    }
    sm0[tid] = s0 * (1.f / N_); sm1[tid] = s1 * (1.f / N_);
  }
  __syncthreads();
  if (tid < HID) {
    float a = 0.f;
    for (int cc = 0; cc < C; ++cc) a += sm0[cc] * w11[tid * C + cc];
    h0[tid] = fmaxf(a, 0.f);
  } else if (tid >= 32 && tid < 32 + HID) {
    int j = tid - 32;
    float a = 0.f;
    for (int cc = 0; cc < C; ++cc) a += sm1[cc] * w21[j * C + cc];
    h1[j] = fmaxf(a, 0.f);
  }
  __syncthreads();
  if (tid == 0) {
    float a = 0.f;
    for (int j = 0; j < HID; ++j) a += h0[j] * w12[j];
    sout[b] = sigmoidf_(a);
  } else if (tid == 32) {
    float a = 0.f;
    for (int j = 0; j < HID; ++j) a += h1[j] * w22[j];
    sout[B_ + b] = sigmoidf_(a);
  }
}

// ---------------------------------------------------------------------------
// gate combine -> cand fp32 + candb bf16 + rbuf fp32
__global__ __launch_bounds__(256) void gate_combine_b2(const float* __restrict__ a0,
                                                       const float* __restrict__ a1,
                                                       const float* __restrict__ s12,
                                                       const float* __restrict__ x,
                                                       const float* __restrict__ st,
                                                       float* __restrict__ cand,
                                                       u16* __restrict__ candb,
                                                       float* __restrict__ rbuf) {
  size_t t = (size_t)blockIdx.x * 256 + threadIdx.x;
  if (t >= (size_t)B_ * N_ * 64) return;
  int c = (int)(t & 63);
  int b = (int)((t >> 6) & 63);
  int n = (int)(t >> 12);
  float s1 = s12[b], s2 = s12[B_ + b];
  size_t nb = (size_t)n * B_ + b;
  size_t i128 = nb * 128;
  float uz = s1 * lrelu(a0[i128 + c]) + s2 * lrelu(a1[i128 + c]);
  float ur = s1 * lrelu(a0[i128 + 64 + c]) + s2 * lrelu(a1[i128 + 64 + c]);
  float z = sigmoidf_(uz);
  float r = sigmoidf_(ur);
  float stv = st[((size_t)b * N_ + n) * 64 + c];
  float zs = z * stv;
  cand[nb * CIN_ + 32 + c] = zs;
  candb[nb * CIN_ + 32 + c] = f2b(zs);
  rbuf[nb * 64 + c] = r;
  if (c < 32) {
    float xv = x[((size_t)b * N_ + n) * 32 + c];
    cand[nb * CIN_ + c] = xv;
    candb[nb * CIN_ + c] = f2b(xv);
  }
}

__global__ __launch_bounds__(256) void final_h(const float* __restrict__ a0,
                                               const float* __restrict__ a1,
                                               const float* __restrict__ s12,
                                               const float* __restrict__ rbuf,
                                               const float* __restrict__ st,
                                               float* __restrict__ out) {
  size_t t = (size_t)blockIdx.x * 256 + threadIdx.x;
  if (t >= (size_t)B_ * N_ * 64) return;
  int o = (int)(t & 63);
  int n = (int)((t >> 6) & 1023);
  int b = (int)(t >> 16);
  float s1 = s12[b], s2 = s12[B_ + b];
  size_t nb = ((size_t)n * B_ + b) * 64 + o;
  float u = s1 * lrelu(a0[nb]) + s2 * lrelu(a1[nb]);
  float hc = tanhf(u);
  float r = rbuf[nb];
  out[t] = r * st[t] + (1.f - r) * hc;
}

// ---------------------------------------------------------------------------
extern "C" void kernel_launch(void* const* d_in, const int* in_sizes, int n_in,
                              void* d_out, int out_size, void* d_ws, size_t ws_size,
                              hipStream_t stream) {
  const float* x       = (const float*)d_in[0];
  const float* state   = (const float*)d_in[1];
  const float* emb     = (const float*)d_in[2];
  const float* Ltil    = (const float*)d_in[3];
  const float* cheb    = (const float*)d_in[4];
  const float* g_wpool = (const float*)d_in[5];
  const float* g_bpool = (const float*)d_in[6];
  const float* g_iw    = (const float*)d_in[7];
  const float* g_ib    = (const float*)d_in[8];
  const float* g_gw    = (const float*)d_in[9];
  const float* g_gb    = (const float*)d_in[10];
  const float* g_a1w1  = (const float*)d_in[11];
  const float* g_a1w2  = (const float*)d_in[12];
  const float* g_a2w1  = (const float*)d_in[13];
  const float* g_a2w2  = (const float*)d_in[14];
  const float* u_wpool = (const float*)d_in[15];
  const float* u_bpool = (const float*)d_in[16];
  const float* u_iw    = (const float*)d_in[17];
  const float* u_ib    = (const float*)d_in[18];
  const float* u_gw    = (const float*)d_in[19];
  const float* u_gb    = (const float*)d_in[20];
  const float* u_a1w1  = (const float*)d_in[21];
  const float* u_a1w2  = (const float*)d_in[22];
  const float* u_a2w1  = (const float*)d_in[23];
  const float* u_a2w2  = (const float*)d_in[24];
  float* out = (float*)d_out;

  // workspace (float offsets), ~240.3 MB (same layout as R17)
  float* ws    = (float*)d_ws;
  float* inp   = ws;                       // [65536][96] fp32 (later cand)
  u16*   inpb  = (u16*)(ws + 6291456);     // [65536][96] bf16 (later candb)
  float* t12   = ws + 9437184;             // [2048][6144] fp32; Zbuf overlays;
                                           //   also L2-partials P[3][1M] at init
  u16*   Zbuf  = (u16*)t12;                //   gate [65536][384] bf16 (exact fit)
  u16*   Wbuf  = (u16*)(ws + 22020096);    // update Wt [1024][64][288] bf16
  u16*   Wbuf128 = Wbuf;                   // gate Wt [1024][128][288] bf16 (overlay)
  u16*   Btp   = (u16*)(ws + 31457280);    // [6144][1024] bf16
  u16*   Zt    = Wbuf;                     // overlay Wbuf+Btp: [24576][1024]
  float* acc1  = ws + 34603008;            // [n,b,128]
  float* acc0  = ws + 42991616;            // [n,b,128]
  u16*   LbStk = (u16*)(ws + 51380224);    // [2048][1024] bf16 (Lhi ; L2)
  u16*   chebb = (u16*)(ws + 52428800);    // [3][1024][1024] bf16
  float* s12   = ws + 54001664;
  float* s12u  = ws + 54001792;
  float* part0 = ws + 54001920;            // [64][16][128]
  float* part1 = ws + 54132992;
  float* rbuf  = ws + 54264064;            // [n,b,64]
  u16*   Vbg   = (u16*)(ws + 58458368);    // [384][96] = 18432 fl
  float* bag   = ws + 58476800;            // [384]
  u16*   Vbu   = (u16*)(ws + 58477184);    // [256][96] = 12288 fl
  float* bau   = ws + 58489472;            // [256]
  u16*   LhiT  = (u16*)(ws + 58489728);    // [1024][1024] bf16
  u16*   LloT  = (u16*)(ws + 59014016);    // [1024][1024] bf16
  u16*   Llo   = (u16*)(ws + 59538304);    // [1024][1024] bf16  (end 60,062,592)
  float* wpTg  = ws + 58489728;            // overlay LhiT+ (dead after l2p)
  float* wpTu  = ws + 59079552;

  dim3 blk(256);
  dim3 blk512(512);

  // ---- init ----
  split_hilo<<<1024, blk, 0, stream>>>(Ltil, LbStk, Llo, 262144);
  transpose_split<<<dim3(32, 32), blk, 0, stream>>>(Ltil, LhiT, LloT);
  mfma_l2p<<<dim3(16, 16, 3), blk, 0, stream>>>(LbStk, Llo, LhiT, LloT, t12);
  wpool_tr<<<dim3(9, 4, 16), blk, 0, stream>>>(g_wpool, wpTg, 128);
  wpool_tr<<<dim3(9, 2, 16), blk, 0, stream>>>(u_wpool, wpTu, 64);
  l2_finish<<<1024, blk, 0, stream>>>(t12, LbStk + 1048576);
  conv_f2b<<<3072, blk, 0, stream>>>(cheb, chebb, 786432);

  // ---- gate AVWGCN (dim_out = 128) ----
  concat_bf2<<<24576, blk, 0, stream>>>(x, state, inp, inpb);
  transpose_b2b<<<dim3(3, 32, 64), blk, 0, stream>>>(inpb, 96, 96, Btp);
  mfma_stack_w<<<dim3(24, 16), blk512, 0, stream>>>(LbStk, Btp, t12, 6144);
  vgen2<128, 7><<<384, dim3(128), 0, stream>>>(g_gw, g_iw, g_ib, 384, Vbg, bag);
  weightgen5<36864><<<dim3(144, 16), blk, 0, stream>>>(emb, wpTg, Wbuf128);
  pernode10<128><<<1024, blk, 0, stream>>>(inp, t12, Wbuf128, emb, g_bpool, acc0);
  zgemm<<<dim3(3, 512), blk, 0, stream>>>(inpb, Vbg, bag, Zbuf, 384);   // overlays t12 (dead)
  transpose_b2b<<<dim3(12, 32, 64), blk, 0, stream>>>(Zbuf, 384, 384, Zt);  // kills Wbuf/Btp
  mfma_k3<<<dim3(64, 8), blk512, 0, stream>>>(chebb, Zt, g_gb, acc1, 8192, 7);
  att_reduce<128><<<dim3(16, 64), blk, 0, stream>>>(acc0, acc1, part0, part1);
  att_finish<128, 8><<<64, blk, 0, stream>>>(part0, part1, g_a1w1, g_a1w2, g_a2w1, g_a2w2, s12);
  gate_combine_b2<<<16384, blk, 0, stream>>>(acc0, acc1, s12, x, state, inp, inpb, rbuf);

  // ---- update AVWGCN (dim_out = 64), input = cand/candb ----
  transpose_b2b<<<dim3(3, 32, 64), blk, 0, stream>>>(inpb, 96, 96, Btp);
  mfma_stack_w<<<dim3(24, 16), blk512, 0, stream>>>(LbStk, Btp, t12, 6144);
  vgen2<64, 6><<<256, dim3(128), 0, stream>>>(u_gw, u_iw, u_ib, 192, Vbu, bau);
  weightgen5<18432><<<dim3(72, 16), blk, 0, stream>>>(emb, wpTu, Wbuf);
  pernode10<64><<<1024, blk, 0, stream>>>(inp, t12, Wbuf, emb, u_bpool, acc0);
  zgemm<<<dim3(2, 512), blk, 0, stream>>>(inpb, Vbu, bau, Zbuf, 256);
  transpose_b2b<<<dim3(6, 32, 64), blk, 0, stream>>>(Zbuf, 256, 192, Zt);
  mfma_k3<<<dim3(32, 8), blk512, 0, stream>>>(chebb, Zt, u_gb, acc1, 4096, 6);
  att_reduce<64><<<dim3(16, 64), blk, 0, stream>>>(acc0, acc1, part0, part1);
  att_finish<64, 4><<<64, blk, 0, stream>>>(part0, part1, u_a1w1, u_a1w2, u_a2w1, u_a2w2, s12u);
  final_h<<<16384, blk, 0, stream>>>(acc0, acc1, s12u, rbuf, state, out);
}

// Round 12
// 616.146 us; speedup vs baseline: 1.0400x; 1.0271x over previous
//
#include <hip/hip_runtime.h>
#include <hip/hip_bf16.h>
#include <math.h>

// RGSLCell on MI355X. R20 = R19 + stack GEMMs moved to the R19-proven shape:
//  R19's A/B showed 128x128/8-wave/acc[4][2]/BK=64/64KB-LDS @ 2 blocks/CU
//  beats 128x256/96KB @ 1 block/CU (59.5 vs 63.5us on the gate cheb GEMM).
//  The two mfma_stack_w calls were the last GEMMs on the losing shape
//  (grid 384 = 1.5 rounds, half-idle tail). R20: mfma_stack8 = mfma_k3
//  minus kb/brow (K=1024, plain B rows), grid (48,16)=768 blocks @ 2/CU.
//  Ascending K-chain unchanged -> bit-identical numerics.
// Everything else identical to R19 (632.9us, absmax 0.078125).

#define B_  64
#define N_  1024
#define CIN_ 96
#define R_  288

typedef __attribute__((ext_vector_type(8))) short bf16x8;
typedef __attribute__((ext_vector_type(4))) float f32x4;
typedef unsigned short u16;
typedef unsigned int u32;

__device__ __forceinline__ float lrelu(float v) { return v >= 0.f ? v : 0.01f * v; }
__device__ __forceinline__ float sigmoidf_(float u) { return 1.f / (1.f + expf(-u)); }
// round-to-nearest-even fp32 -> bf16
__device__ __forceinline__ u16 f2b(float f) {
  union { float f; u32 u; } c; c.f = f;
  u32 u = c.u;
  return (u16)((u + 0x7FFFu + ((u >> 16) & 1u)) >> 16);
}
__device__ __forceinline__ float b2f(u16 u) {
  union { u32 x; float f; } c; c.x = ((u32)u) << 16; return c.f;
}
__device__ __forceinline__ void gload_lds16(const u16* gp, u16* lp) {
  __builtin_amdgcn_global_load_lds((const __attribute__((address_space(1))) u32*)gp,
                                   (__attribute__((address_space(3))) u32*)lp, 16, 0, 0);
}

// ---------------------------------------------------------------------------
// concat: inp fp32 AND inpb bf16, layout [(n*64+b)][96]
__global__ __launch_bounds__(256) void concat_bf2(const float* __restrict__ x,
                                                  const float* __restrict__ st,
                                                  float* __restrict__ inp,
                                                  u16* __restrict__ inpb) {
  size_t t = (size_t)blockIdx.x * 256 + threadIdx.x;
  if (t >= (size_t)B_ * N_ * CIN_) return;
  int i = (int)(t % CIN_);
  size_t v = t / CIN_;
  size_t b = v & 63, n = v >> 6;
  float f = (i < 32) ? x[(b * N_ + n) * 32 + i] : st[(b * N_ + n) * 64 + (i - 32)];
  inp[t] = f;
  inpb[t] = f2b(f);
}

// fp32 -> bf16 flat convert (cheb)
__global__ __launch_bounds__(256) void conv_f2b(const float* __restrict__ in,
                                                u16* __restrict__ out, int n4) {
  int t = blockIdx.x * 256 + threadIdx.x;
  if (t >= n4) return;
  float4 v = ((const float4*)in)[t];
  ushort4 o;
  o.x = f2b(v.x); o.y = f2b(v.y); o.z = f2b(v.z); o.w = f2b(v.w);
  ((ushort4*)out)[t] = o;
}

// split fp32 -> (hi, lo) bf16 planes
__global__ __launch_bounds__(256) void split_hilo(const float* __restrict__ in,
                                                  u16* __restrict__ hi,
                                                  u16* __restrict__ lo, int n4) {
  int t = blockIdx.x * 256 + threadIdx.x;
  if (t >= n4) return;
  float4 v = ((const float4*)in)[t];
  ushort4 h, l;
  h.x = f2b(v.x); l.x = f2b(v.x - b2f(h.x));
  h.y = f2b(v.y); l.y = f2b(v.y - b2f(h.y));
  h.z = f2b(v.z); l.z = f2b(v.z - b2f(h.z));
  h.w = f2b(v.w); l.w = f2b(v.w - b2f(h.w));
  ((ushort4*)hi)[t] = h;
  ((ushort4*)lo)[t] = l;
}

// transpose fp32 [1024][1024] -> (hiT, loT) bf16 planes of L^T
__global__ __launch_bounds__(256) void transpose_split(const float* __restrict__ in,
                                                       u16* __restrict__ hiT,
                                                       u16* __restrict__ loT) {
  __shared__ float t[32][33];
  const int tid = threadIdx.x;
  const int j0 = blockIdx.x * 32, r0 = blockIdx.y * 32;
  const int tc = tid & 31, tr = tid >> 5;
#pragma unroll
  for (int q = 0; q < 4; ++q)
    t[tr + q * 8][tc] = in[(size_t)(r0 + tr + q * 8) * 1024 + j0 + tc];
  __syncthreads();
  const int jj = tid >> 3, rq = (tid & 7) * 4;
  ushort4 h, l;
#pragma unroll
  for (int q = 0; q < 4; ++q) {
    float v = t[rq + q][jj];
    u16 hh = f2b(v);
    ((u16*)&h)[q] = hh;
    ((u16*)&l)[q] = f2b(v - b2f(hh));
  }
  *(ushort4*)(hiT + (size_t)(j0 + jj) * N_ + r0 + rq) = h;
  *(ushort4*)(loT + (size_t)(j0 + jj) * N_ + r0 + rq) = l;
}

// transpose bf16 [(n*64+b)][Zs] -> bf16 [(b*Ctot+c)][1024]
__global__ __launch_bounds__(256) void transpose_b2b(const u16* __restrict__ Z, int Zs,
                                                     int Ctot, u16* __restrict__ Zt) {
  __shared__ u16 t[32][36];
  const int tid = threadIdx.x;
  const int c0 = blockIdx.x * 32, n0 = blockIdx.y * 32, b = blockIdx.z;
  {
    const int i = tid >> 3, c4 = (tid & 7) * 4;
    ushort4 v = *(const ushort4*)(Z + ((size_t)(n0 + i) * 64 + b) * Zs + c0 + c4);
    t[i][c4] = v.x; t[i][c4 + 1] = v.y; t[i][c4 + 2] = v.z; t[i][c4 + 3] = v.w;
  }
  __syncthreads();
  {
    const int c = tid >> 3, n4 = (tid & 7) * 4;
    ushort4 o;
    o.x = t[n4][c]; o.y = t[n4 + 1][c]; o.z = t[n4 + 2][c]; o.w = t[n4 + 3][c];
    *(ushort4*)(Zt + (size_t)(b * Ctot + c0 + c) * 1024 + n0 + n4) = o;
  }
}

// wpool transpose: wpT[d][o][r] = wp[d][r][o]. grid (288/32, OW/32, 16).
__global__ __launch_bounds__(256) void wpool_tr(const float* __restrict__ wp,
                                                float* __restrict__ wpT, int OW) {
  __shared__ float t[32][33];
  const int tid = threadIdx.x;
  const int r0 = blockIdx.x * 32, o0 = blockIdx.y * 32, d = blockIdx.z;
  const size_t base = (size_t)d * 288 * OW;
  const int c = tid & 31, q0 = tid >> 5;
#pragma unroll
  for (int q = 0; q < 4; ++q)
    t[q0 + q * 8][c] = wp[base + (size_t)(r0 + q0 + q * 8) * OW + o0 + c];
  __syncthreads();
#pragma unroll
  for (int q = 0; q < 4; ++q)
    wpT[base + (size_t)(o0 + q0 + q * 8) * 288 + r0 + c] = t[c][q0 + q * 8];
}

// ---------------------------------------------------------------------------
// compensated L2, phase-split: P[z] = (z==0 ? Lhi@Lhi : z==1 ? Llo@Lhi : Lhi@Llo)
__global__ __launch_bounds__(256) void mfma_l2p(const u16* __restrict__ Lhi,
                                                const u16* __restrict__ Llo,
                                                const u16* __restrict__ LhiT,
                                                const u16* __restrict__ LloT,
                                                float* __restrict__ P) {
  __shared__ u16 Asl[64 * 64];
  __shared__ u16 Bsl[64 * 64];
  const int tid = threadIdx.x;
  const int w = tid >> 6, lane = tid & 63;
  const int m0 = blockIdx.y * 64, n0 = blockIdx.x * 64;
  const int ph = blockIdx.z;
  const int wr = w >> 1, wc = w & 1;
  const int sr = lane >> 3, so = lane & 7;
  const int cl = lane & 15, q4 = lane >> 4;
  f32x4 acc[2][2] = {};

  const u16* A = (ph == 1) ? Llo : Lhi;
  const u16* B = (ph == 2) ? LloT : LhiT;
  for (int k0 = 0; k0 < 1024; k0 += 64) {
    __syncthreads();
#pragma unroll
    for (int i = 0; i < 2; ++i) {
      const int r = i * 32 + w * 8 + sr;
      const int o = so ^ (r & 7);
      gload_lds16(A + (size_t)(m0 + r) * 1024 + k0 + o * 8, Asl + (i * 32 + w * 8) * 64);
      gload_lds16(B + (size_t)(n0 + r) * 1024 + k0 + o * 8, Bsl + (i * 32 + w * 8) * 64);
    }
    __syncthreads();
#pragma unroll
    for (int kk = 0; kk < 2; ++kk) {
      bf16x8 af[2], bfr[2];
#pragma unroll
      for (int mi = 0; mi < 2; ++mi) {
        const int ra = wr * 32 + mi * 16 + cl;
        af[mi] = *(const bf16x8*)(Asl + ra * 64 + ((kk * 4 + q4) ^ (ra & 7)) * 8);
      }
#pragma unroll
      for (int ni = 0; ni < 2; ++ni) {
        const int rb = wc * 32 + ni * 16 + cl;
        bfr[ni] = *(const bf16x8*)(Bsl + rb * 64 + ((kk * 4 + q4) ^ (rb & 7)) * 8);
      }
#pragma unroll
      for (int mi = 0; mi < 2; ++mi)
#pragma unroll
        for (int ni = 0; ni < 2; ++ni)
          acc[mi][ni] = __builtin_amdgcn_mfma_f32_16x16x32_bf16(af[mi], bfr[ni], acc[mi][ni], 0, 0, 0);
    }
  }
  float* Pz = P + ((size_t)ph << 20);
#pragma unroll
  for (int mi = 0; mi < 2; ++mi)
#pragma unroll
    for (int ni = 0; ni < 2; ++ni) {
      const int j = n0 + wc * 32 + ni * 16 + cl;
#pragma unroll
      for (int r = 0; r < 4; ++r) {
        const int m = m0 + wr * 32 + mi * 16 + q4 * 4 + r;
        Pz[(size_t)m * 1024 + j] = acc[mi][ni][r];
      }
    }
}

// combine the 3 partials: Y = bf16(2*(P0+P1+P2) - I)
__global__ __launch_bounds__(256) void l2_finish(const float* __restrict__ P,
                                                 u16* __restrict__ Y) {
  int t = blockIdx.x * 256 + threadIdx.x;   // 262144 float4 groups
  float4 a = ((const float4*)P)[t];
  float4 b = ((const float4*)(P + 1048576))[t];
  float4 c = ((const float4*)(P + 2097152))[t];
  int e = t << 2;
  int m = e >> 10, j = e & 1023;
  ushort4 o;
  o.x = f2b(2.f * (a.x + b.x + c.x) - (m == j     ? 1.f : 0.f));
  o.y = f2b(2.f * (a.y + b.y + c.y) - (m == j + 1 ? 1.f : 0.f));
  o.z = f2b(2.f * (a.z + b.z + c.z) - (m == j + 2 ? 1.f : 0.f));
  o.w = f2b(2.f * (a.w + b.w + c.w) - (m == j + 3 ? 1.f : 0.f));
  ((ushort4*)Y)[t] = o;
}

// ---------------------------------------------------------------------------
// R20: stack GEMM on the R19-proven shape: Y[2048][J] = A@B, 128x128 tile,
// 8 waves (2x4), acc[4][2], BK=64, 64KB LDS, counted vmcnt(4).
// Grid (J/128=48, 16) = 768 blocks = 2 blocks/CU.
__global__ __launch_bounds__(512) void mfma_stack8(const u16* __restrict__ A,
                                                   const u16* __restrict__ Bt,
                                                   float* __restrict__ Y, int J) {
  __shared__ u16 Asl[2][128 * 64];
  __shared__ u16 Bsl[2][128 * 64];
  const int tid = threadIdx.x;
  const int w = tid >> 6, lane = tid & 63;    // w 0..7
  const int m0 = blockIdx.y * 128, n0 = blockIdx.x * 128;
  const int wr = w >> 2, wc = w & 3;          // wr 0..1, wc 0..3
  const int sr = lane >> 3, so = lane & 7;
  const int cl = lane & 15, q4 = lane >> 4;
  f32x4 acc[4][2] = {};

  auto STAGE = [&](u16* Ad, u16* Bd, int k0) {
#pragma unroll
    for (int i = 0; i < 2; ++i) {
      const int r = i * 64 + w * 8 + sr;
      const int o = so ^ (r & 7);
      gload_lds16(A + (size_t)(m0 + r) * 1024 + k0 + o * 8, Ad + (i * 64 + w * 8) * 64);
      gload_lds16(Bt + (size_t)(n0 + r) * 1024 + k0 + o * 8, Bd + (i * 64 + w * 8) * 64);
    }
  };
  auto COMPUTE = [&](const u16* As, const u16* Bs) {
#pragma unroll
    for (int kk = 0; kk < 2; ++kk) {
      bf16x8 af[4], bfr[2];
#pragma unroll
      for (int mi = 0; mi < 4; ++mi) {
        const int ra = wr * 64 + mi * 16 + cl;
        af[mi] = *(const bf16x8*)(As + ra * 64 + ((kk * 4 + q4) ^ (ra & 7)) * 8);
      }
#pragma unroll
      for (int ni = 0; ni < 2; ++ni) {
        const int rb = wc * 32 + ni * 16 + cl;
        bfr[ni] = *(const bf16x8*)(Bs + rb * 64 + ((kk * 4 + q4) ^ (rb & 7)) * 8);
      }
#pragma unroll
      for (int mi = 0; mi < 4; ++mi)
#pragma unroll
        for (int ni = 0; ni < 2; ++ni)
          acc[mi][ni] = __builtin_amdgcn_mfma_f32_16x16x32_bf16(af[mi], bfr[ni], acc[mi][ni], 0, 0, 0);
    }
  };

  STAGE(Asl[0], Bsl[0], 0);
  for (int k0 = 0; k0 < 1024; k0 += 128) {
    STAGE(Asl[1], Bsl[1], k0 + 64);
    asm volatile("s_waitcnt vmcnt(4)" ::: "memory");
    __builtin_amdgcn_s_barrier();
    __builtin_amdgcn_sched_barrier(0);
    COMPUTE(Asl[0], Bsl[0]);
    asm volatile("s_waitcnt lgkmcnt(0)" ::: "memory");
    __builtin_amdgcn_s_barrier();
    __builtin_amdgcn_sched_barrier(0);
    if (k0 + 128 < 1024) {
      STAGE(Asl[0], Bsl[0], k0 + 128);
      asm volatile("s_waitcnt vmcnt(4)" ::: "memory");
    } else {
      asm volatile("s_waitcnt vmcnt(0)" ::: "memory");
    }
    __builtin_amdgcn_s_barrier();
    __builtin_amdgcn_sched_barrier(0);
    COMPUTE(Asl[1], Bsl[1]);
    asm volatile("s_waitcnt lgkmcnt(0)" ::: "memory");
    __builtin_amdgcn_s_barrier();
    __builtin_amdgcn_sched_barrier(0);
  }
#pragma unroll
  for (int mi = 0; mi < 4; ++mi)
#pragma unroll
    for (int ni = 0; ni < 2; ++ni) {
      const int j = n0 + wc * 32 + ni * 16 + cl;
#pragma unroll
      for (int r = 0; r < 4; ++r) {
        const int m = m0 + wr * 64 + mi * 16 + q4 * 4 + r;
        Y[(size_t)m * J + j] = acc[mi][ni][r];
      }
    }
}

// ---------------------------------------------------------------------------
// vgen2: one block per output row c.
template <int O, int OSH>
__global__ __launch_bounds__(128) void vgen2(const float* __restrict__ gw,
                                             const float* __restrict__ iw,
                                             const float* __restrict__ ib,
                                             int Ctot,
                                             u16* __restrict__ Vb,
                                             float* __restrict__ ball) {
  const int c = blockIdx.x;
  const int col = threadIdx.x;
  if (c >= Ctot) {  // zero-pad (block-uniform branch)
    if (col < 96) Vb[(size_t)c * 96 + col] = 0;
    else if (col == 96) ball[c] = 0.f;
    return;
  }
  __shared__ float sg[O];
  const int o = c & (O - 1), k = c >> OSH;
  const float* g = gw + (size_t)o * (3 * O) + (size_t)k * O;
  for (int e = col; e < O; e += 128) sg[e] = g[e];
  __syncthreads();
  if (col < 96) {
    float s = 0.f;
#pragma unroll
    for (int j = 0; j < O; ++j) s += sg[j] * iw[j * 96 + col];
    Vb[(size_t)c * 96 + col] = f2b(s);
  } else if (col == 96) {
    float s = 0.f;
#pragma unroll
    for (int j = 0; j < O; ++j) s += sg[j] * ib[j];
    ball[c] = s;
  }
}

// ---------------------------------------------------------------------------
// zgemm: Z[M][Zs] bf16 = A[M][96] @ Vb^T + ball. 128x128 tile, BK=32 x 3.
__global__ __launch_bounds__(256) void zgemm(const u16* __restrict__ A,
                                             const u16* __restrict__ Bt,
                                             const float* __restrict__ ball,
                                             u16* __restrict__ Z, int Zs) {
  __shared__ u16 Asl[128 * 32];
  __shared__ u16 Bsl[128 * 32];
  const int tid = threadIdx.x;
  const int w = tid >> 6, lane = tid & 63;
  const int m0 = blockIdx.y * 128, n0 = blockIdx.x * 128;
  const int wr = w >> 1, wc = w & 1;
  const int sr = lane >> 2, so = lane & 3;
  const int cl = lane & 15, q4 = lane >> 4;
  f32x4 acc[4][4] = {};
  for (int k0 = 0; k0 < 96; k0 += 32) {
    __syncthreads();
#pragma unroll
    for (int i = 0; i < 2; ++i) {
      const int r = i * 64 + w * 16 + sr;
      const int o = so ^ (r & 3);
      gload_lds16(A + (size_t)(m0 + r) * 96 + k0 + o * 8, Asl + (i * 64 + w * 16) * 32);
      gload_lds16(Bt + (size_t)(n0 + r) * 96 + k0 + o * 8, Bsl + (i * 64 + w * 16) * 32);
    }
    __syncthreads();
    bf16x8 af[4], bfr[4];
#pragma unroll
    for (int mi = 0; mi < 4; ++mi) {
      const int ra = wr * 64 + mi * 16 + cl;
      af[mi] = *(const bf16x8*)(Asl + ra * 32 + (q4 ^ (ra & 3)) * 8);
    }
#pragma unroll
    for (int ni = 0; ni < 4; ++ni) {
      const int rb = wc * 64 + ni * 16 + cl;
      bfr[ni] = *(const bf16x8*)(Bsl + rb * 32 + (q4 ^ (rb & 3)) * 8);
    }
#pragma unroll
    for (int mi = 0; mi < 4; ++mi)
#pragma unroll
      for (int ni = 0; ni < 4; ++ni)
        acc[mi][ni] = __builtin_amdgcn_mfma_f32_16x16x32_bf16(af[mi], bfr[ni], acc[mi][ni], 0, 0, 0);
  }
#pragma unroll
  for (int mi = 0; mi < 4; ++mi)
#pragma unroll
    for (int ni = 0; ni < 4; ++ni) {
      const int c = n0 + wc * 64 + ni * 16 + cl;
      const float bb = ball[c];
#pragma unroll
      for (int r = 0; r < 4; ++r) {
        const int m = m0 + wr * 64 + mi * 16 + q4 * 4 + r;
        Z[(size_t)m * Zs + c] = f2b(acc[mi][ni][r] + bb);
      }
    }
}

// ---------------------------------------------------------------------------
// stacked-K cheb GEMM, 128x128, 8 waves (2x4), acc[4][2], BK=64, 64KB LDS.
// GATE: grid (64,8); UPDATE: grid (32,8).
__global__ __launch_bounds__(512) void mfma_k3(const u16* __restrict__ A3,
                                               const u16* __restrict__ Zt,
                                               const float* __restrict__ gb,
                                               float* __restrict__ Y,
                                               int J, int obits) {
  __shared__ u16 Asl[2][128 * 64];
  __shared__ u16 Bsl[2][128 * 64];
  const int tid = threadIdx.x;
  const int w = tid >> 6, lane = tid & 63;    // w 0..7
  const int m0 = blockIdx.y * 128, n0 = blockIdx.x * 128;
  const int wr = w >> 2, wc = w & 3;          // wr 0..1, wc 0..3
  const int sr = lane >> 3, so = lane & 7;
  const int cl = lane & 15, q4 = lane >> 4;
  const int omask = (1 << obits) - 1;
  f32x4 acc[4][2] = {};

  auto STAGE = [&](u16* Ad, u16* Bd, int k0) {
    const int kb = k0 >> 10, ko = k0 & 1023;
#pragma unroll
    for (int i = 0; i < 2; ++i) {
      const int r = i * 64 + w * 8 + sr;
      const int o = so ^ (r & 7);
      gload_lds16(A3 + (size_t)kb * 1048576 + (size_t)(m0 + r) * 1024 + ko + o * 8,
                  Ad + (i * 64 + w * 8) * 64);
      const int jp = n0 + r;
      const int brow = (((jp >> obits) * 3 + kb) << obits) | (jp & omask);
      gload_lds16(Zt + (size_t)brow * 1024 + ko + o * 8, Bd + (i * 64 + w * 8) * 64);
    }
  };
  auto COMPUTE = [&](const u16* As, const u16* Bs) {
#pragma unroll
    for (int kk = 0; kk < 2; ++kk) {
      bf16x8 af[4], bfr[2];
#pragma unroll
      for (int mi = 0; mi < 4; ++mi) {
        const int ra = wr * 64 + mi * 16 + cl;
        af[mi] = *(const bf16x8*)(As + ra * 64 + ((kk * 4 + q4) ^ (ra & 7)) * 8);
      }
#pragma unroll
      for (int ni = 0; ni < 2; ++ni) {
        const int rb = wc * 32 + ni * 16 + cl;
        bfr[ni] = *(const bf16x8*)(Bs + rb * 64 + ((kk * 4 + q4) ^ (rb & 7)) * 8);
      }
#pragma unroll
      for (int mi = 0; mi < 4; ++mi)
#pragma unroll
        for (int ni = 0; ni < 2; ++ni)
          acc[mi][ni] = __builtin_amdgcn_mfma_f32_16x16x32_bf16(af[mi], bfr[ni], acc[mi][ni], 0, 0, 0);
    }
  };

  STAGE(Asl[0], Bsl[0], 0);
  for (int k0 = 0; k0 < 3072; k0 += 128) {
    STAGE(Asl[1], Bsl[1], k0 + 64);
    asm volatile("s_waitcnt vmcnt(4)" ::: "memory");
    __builtin_amdgcn_s_barrier();
    __builtin_amdgcn_sched_barrier(0);
    COMPUTE(Asl[0], Bsl[0]);
    asm volatile("s_waitcnt lgkmcnt(0)" ::: "memory");
    __builtin_amdgcn_s_barrier();
    __builtin_amdgcn_sched_barrier(0);
    if (k0 + 128 < 3072) {
      STAGE(Asl[0], Bsl[0], k0 + 128);
      asm volatile("s_waitcnt vmcnt(4)" ::: "memory");
    } else {
      asm volatile("s_waitcnt vmcnt(0)" ::: "memory");
    }
    __builtin_amdgcn_s_barrier();
    __builtin_amdgcn_sched_barrier(0);
    COMPUTE(Asl[1], Bsl[1]);
    asm volatile("s_waitcnt lgkmcnt(0)" ::: "memory");
    __builtin_amdgcn_s_barrier();
    __builtin_amdgcn_sched_barrier(0);
  }
#pragma unroll
  for (int mi = 0; mi < 4; ++mi)
#pragma unroll
    for (int ni = 0; ni < 2; ++ni) {
      const int j = n0 + wc * 32 + ni * 16 + cl;
      const float bb = gb[j & omask];
#pragma unroll
      for (int r = 0; r < 4; ++r) {
        const int m = m0 + wr * 64 + mi * 16 + q4 * 4 + r;
        Y[(size_t)m * J + j] = acc[mi][ni][r] + bb;
      }
    }
}

// ---------------------------------------------------------------------------
// weightgen5: Wt[n][SZ] bf16 = sum_d emb[n][d]*wpoolT[d][SZ] (linear; SZ=OW*288)
template <int SZ>
__global__ __launch_bounds__(256) void weightgen5(const float* __restrict__ emb,
                                                  const float* __restrict__ wpT,
                                                  u16* __restrict__ W) {
  const int tid = threadIdx.x;
  const int ro = blockIdx.x * 256 + tid;
  const int n0 = blockIdx.y * 64;
  __shared__ float semb[64][17];
  for (int e = tid; e < 1024; e += 256) semb[e >> 4][e & 15] = emb[(n0 + (e >> 4)) * 16 + (e & 15)];
  __syncthreads();
  float wv[16];
#pragma unroll
  for (int d = 0; d < 16; ++d) wv[d] = wpT[(size_t)d * SZ + ro];
#pragma unroll 4
  for (int n = 0; n < 64; ++n) {
    float s = 0.f;
#pragma unroll
    for (int d = 0; d < 16; ++d) s += semb[n][d] * wv[d];
    W[(size_t)(n0 + n) * SZ + ro] = f2b(s);
  }
}

// pernode10: per-node GEMM on the MATRIX pipe. Block per node, 4 waves.
// C[o][b] = Wt[n] @ X^T. X fp32 -> hi/lo bf16 in LDS. 9 chunks x {hi,lo}.
template <int OW>
__global__ __launch_bounds__(256) void pernode10(const float* __restrict__ xa,
                                                 const float* __restrict__ xbc,
                                                 const u16* __restrict__ Wt,
                                                 const float* __restrict__ emb,
                                                 const float* __restrict__ bpool,
                                                 float* __restrict__ outp) {
  constexpr int MT = OW / 64;            // o 16-tiles per wave (2 gate, 1 upd)
  const int n = blockIdx.x;
  const int tid = threadIdx.x;
  const int w = tid >> 6, lane = tid & 63;
  const int cl = lane & 15, q4 = lane >> 4;
  __shared__ u16 sWt[OW * 32];
  __shared__ u16 sXh[64 * 32];
  __shared__ u16 sXl[64 * 32];
  __shared__ float semb[16];
  if (tid < 16) semb[tid] = emb[n * 16 + tid];
  f32x4 acc[MT][4] = {};
  const u16* Wn = Wt + (size_t)n * (OW * 288);
  const int xb = tid >> 2, rg = tid & 3;  // X staging map: b row, 8-r group

  for (int c = 0; c < 9; ++c) {
    const int k = c / 3, i0 = (c % 3) * 32;
    const float* xk = (k == 0) ? (xa + (size_t)n * 6144)
                               : (xbc + ((size_t)(k - 1) * 1024 + n) * 6144);
    __syncthreads();
#pragma unroll
    for (int i = 0; i < MT; ++i) {
      const int g = w * MT + i;                  // 16-row group
      const int o = g * 16 + (lane >> 2);
      const int seg = (lane & 3) ^ (o & 3);
      gload_lds16(Wn + (size_t)o * 288 + c * 32 + seg * 8, sWt + g * 512);
    }
    {
      const float* p = xk + (size_t)xb * 96 + i0 + rg * 8;
      float4 v0 = *(const float4*)p;
      float4 v1 = *(const float4*)(p + 4);
      float xv[8] = {v0.x, v0.y, v0.z, v0.w, v1.x, v1.y, v1.z, v1.w};
      bf16x8 h, l;
#pragma unroll
      for (int j = 0; j < 8; ++j) {
        u16 hh = f2b(xv[j]);
        ((u16*)&h)[j] = hh;
        ((u16*)&l)[j] = f2b(xv[j] - b2f(hh));
      }
      const int col = (rg ^ (xb & 3)) * 8;
      *(bf16x8*)(sXh + xb * 32 + col) = h;
      *(bf16x8*)(sXl + xb * 32 + col) = l;
    }
    __syncthreads();
    bf16x8 aw[MT], bh[4], bl[4];
#pragma unroll
    for (int mi = 0; mi < MT; ++mi) {
      const int o = (w * MT + mi) * 16 + cl;
      aw[mi] = *(const bf16x8*)(sWt + o * 32 + ((q4 ^ (o & 3)) * 8));
    }
#pragma unroll
    for (int ni = 0; ni < 4; ++ni) {
      const int b = ni * 16 + cl;
      const int col = (q4 ^ (b & 3)) * 8;
      bh[ni] = *(const bf16x8*)(sXh + b * 32 + col);
      bl[ni] = *(const bf16x8*)(sXl + b * 32 + col);
    }
#pragma unroll
    for (int mi = 0; mi < MT; ++mi)
#pragma unroll
      for (int ni = 0; ni < 4; ++ni)
        acc[mi][ni] = __builtin_amdgcn_mfma_f32_16x16x32_bf16(aw[mi], bh[ni], acc[mi][ni], 0, 0, 0);
#pragma unroll
    for (int mi = 0; mi < MT; ++mi)
#pragma unroll
      for (int ni = 0; ni < 4; ++ni)
        acc[mi][ni] = __builtin_amdgcn_mfma_f32_16x16x32_bf16(aw[mi], bl[ni], acc[mi][ni], 0, 0, 0);
  }
  float4 biasv[MT];
#pragma unroll
  for (int mi = 0; mi < MT; ++mi)
#pragma unroll
    for (int r = 0; r < 4; ++r) {
      const int o = (w * MT + mi) * 16 + q4 * 4 + r;
      float s = 0.f;
#pragma unroll
      for (int d = 0; d < 16; ++d) s += semb[d] * bpool[d * OW + o];
      ((float*)&biasv[mi])[r] = s;
    }
#pragma unroll
  for (int mi = 0; mi < MT; ++mi)
#pragma unroll
    for (int ni = 0; ni < 4; ++ni) {
      const int b = ni * 16 + cl;
      float4 v;
      v.x = acc[mi][ni][0] + biasv[mi].x;
      v.y = acc[mi][ni][1] + biasv[mi].y;
      v.z = acc[mi][ni][2] + biasv[mi].z;
      v.w = acc[mi][ni][3] + biasv[mi].w;
      *(float4*)(outp + ((size_t)n * 64 + b) * OW + (w * MT + mi) * 16 + q4 * 4) = v;
    }
}

// ---------------------------------------------------------------------------
// two-stage attention mean
template <int C>
__global__ __launch_bounds__(256) void att_reduce(const float* __restrict__ A0,
                                                  const float* __restrict__ A1,
                                                  float* __restrict__ part0,
                                                  float* __restrict__ part1) {
  constexpr int C4 = C / 4;
  constexpr int H = 256 / C4;
  const int chunk = blockIdx.x;
  const int b = blockIdx.y;
  const int tid = threadIdx.x;
  const int c4 = tid % C4, h = tid / C4;
  __shared__ float4 r0[256], r1[256];
  float4 s0 = {0.f, 0.f, 0.f, 0.f}, s1 = {0.f, 0.f, 0.f, 0.f};
  const float4* p0 = (const float4*)(A0 + (size_t)b * C) + c4;
  const float4* p1 = (const float4*)(A1 + (size_t)b * C) + c4;
  const size_t stride = (size_t)B_ * C4;
  for (int n = chunk * 64 + h; n < chunk * 64 + 64; n += H) {
    float4 v0 = p0[(size_t)n * stride];
    float4 v1 = p1[(size_t)n * stride];
    s0.x += lrelu(v0.x); s0.y += lrelu(v0.y); s0.z += lrelu(v0.z); s0.w += lrelu(v0.w);
    s1.x += lrelu(v1.x); s1.y += lrelu(v1.y); s1.z += lrelu(v1.z); s1.w += lrelu(v1.w);
  }
  r0[tid] = s0; r1[tid] = s1;
  __syncthreads();
  if (h == 0) {
    for (int hh = 1; hh < H; ++hh) {
      float4 a = r0[c4 + hh * C4], bb = r1[c4 + hh * C4];
      s0.x += a.x; s0.y += a.y; s0.z += a.z; s0.w += a.w;
      s1.x += bb.x; s1.y += bb.y; s1.z += bb.z; s1.w += bb.w;
    }
    ((float4*)(part0 + ((size_t)b * 16 + chunk) * C))[c4] = s0;
    ((float4*)(part1 + ((size_t)b * 16 + chunk) * C))[c4] = s1;
  }
}

template <int C, int HID>
__global__ __launch_bounds__(256) void att_finish(const float* __restrict__ part0,
                                                  const float* __restrict__ part1,
                                                  const float* __restrict__ w11,
                                                  const float* __restrict__ w12,
                                                  const float* __restrict__ w21,
                                                  const float* __restrict__ w22,
                                                  float* __restrict__ sout) {
  const int b = blockIdx.x;
  const int tid = threadIdx.x;
  __shared__ float sm0[C], sm1[C];
  __shared__ float h0[HID], h1[HID];
  if (tid < C) {
    float s0 = 0.f, s1 = 0.f;
    for (int ch = 0; ch < 16; ++ch) {
      s0 += part0[((size_t)b * 16 + ch) * C + tid];
      s1 += part1[((size_t)b * 16 + ch) * C + tid];
    }
    sm0[tid] = s0 * (1.f / N_); sm1[tid] = s1 * (1.f / N_);
  }
  __syncthreads();
  if (tid < HID) {
    float a = 0.f;
    for (int cc = 0; cc < C; ++cc) a += sm0[cc] * w11[tid * C + cc];
    h0[tid] = fmaxf(a, 0.f);
  } else if (tid >= 32 && tid < 32 + HID) {
    int j = tid - 32;
    float a = 0.f;
    for (int cc = 0; cc < C; ++cc) a += sm1[cc] * w21[j * C + cc];
    h1[j] = fmaxf(a, 0.f);
  }
  __syncthreads();
  if (tid == 0) {
    float a = 0.f;
    for (int j = 0; j < HID; ++j) a += h0[j] * w12[j];
    sout[b] = sigmoidf_(a);
  } else if (tid == 32) {
    float a = 0.f;
    for (int j = 0; j < HID; ++j) a += h1[j] * w22[j];
    sout[B_ + b] = sigmoidf_(a);
  }
}

// ---------------------------------------------------------------------------
// gate combine -> cand fp32 + candb bf16 + rbuf fp32
__global__ __launch_bounds__(256) void gate_combine_b2(const float* __restrict__ a0,
                                                       const float* __restrict__ a1,
                                                       const float* __restrict__ s12,
                                                       const float* __restrict__ x,
                                                       const float* __restrict__ st,
                                                       float* __restrict__ cand,
                                                       u16* __restrict__ candb,
                                                       float* __restrict__ rbuf) {
  size_t t = (size_t)blockIdx.x * 256 + threadIdx.x;
  if (t >= (size_t)B_ * N_ * 64) return;
  int c = (int)(t & 63);
  int b = (int)((t >> 6) & 63);
  int n = (int)(t >> 12);
  float s1 = s12[b], s2 = s12[B_ + b];
  size_t nb = (size_t)n * B_ + b;
  size_t i128 = nb * 128;
  float uz = s1 * lrelu(a0[i128 + c]) + s2 * lrelu(a1[i128 + c]);
  float ur = s1 * lrelu(a0[i128 + 64 + c]) + s2 * lrelu(a1[i128 + 64 + c]);
  float z = sigmoidf_(uz);
  float r = sigmoidf_(ur);
  float stv = st[((size_t)b * N_ + n) * 64 + c];
  float zs = z * stv;
  cand[nb * CIN_ + 32 + c] = zs;
  candb[nb * CIN_ + 32 + c] = f2b(zs);
  rbuf[nb * 64 + c] = r;
  if (c < 32) {
    float xv = x[((size_t)b * N_ + n) * 32 + c];
    cand[nb * CIN_ + c] = xv;
    candb[nb * CIN_ + c] = f2b(xv);
  }
}

__global__ __launch_bounds__(256) void final_h(const float* __restrict__ a0,
                                               const float* __restrict__ a1,
                                               const float* __restrict__ s12,
                                               const float* __restrict__ rbuf,
                                               const float* __restrict__ st,
                                               float* __restrict__ out) {
  size_t t = (size_t)blockIdx.x * 256 + threadIdx.x;
  if (t >= (size_t)B_ * N_ * 64) return;
  int o = (int)(t & 63);
  int n = (int)((t >> 6) & 1023);
  int b = (int)(t >> 16);
  float s1 = s12[b], s2 = s12[B_ + b];
  size_t nb = ((size_t)n * B_ + b) * 64 + o;
  float u = s1 * lrelu(a0[nb]) + s2 * lrelu(a1[nb]);
  float hc = tanhf(u);
  float r = rbuf[nb];
  out[t] = r * st[t] + (1.f - r) * hc;
}

// ---------------------------------------------------------------------------
extern "C" void kernel_launch(void* const* d_in, const int* in_sizes, int n_in,
                              void* d_out, int out_size, void* d_ws, size_t ws_size,
                              hipStream_t stream) {
  const float* x       = (const float*)d_in[0];
  const float* state   = (const float*)d_in[1];
  const float* emb     = (const float*)d_in[2];
  const float* Ltil    = (const float*)d_in[3];
  const float* cheb    = (const float*)d_in[4];
  const float* g_wpool = (const float*)d_in[5];
  const float* g_bpool = (const float*)d_in[6];
  const float* g_iw    = (const float*)d_in[7];
  const float* g_ib    = (const float*)d_in[8];
  const float* g_gw    = (const float*)d_in[9];
  const float* g_gb    = (const float*)d_in[10];
  const float* g_a1w1  = (const float*)d_in[11];
  const float* g_a1w2  = (const float*)d_in[12];
  const float* g_a2w1  = (const float*)d_in[13];
  const float* g_a2w2  = (const float*)d_in[14];
  const float* u_wpool = (const float*)d_in[15];
  const float* u_bpool = (const float*)d_in[16];
  const float* u_iw    = (const float*)d_in[17];
  const float* u_ib    = (const float*)d_in[18];
  const float* u_gw    = (const float*)d_in[19];
  const float* u_gb    = (const float*)d_in[20];
  const float* u_a1w1  = (const float*)d_in[21];
  const float* u_a1w2  = (const float*)d_in[22];
  const float* u_a2w1  = (const float*)d_in[23];
  const float* u_a2w2  = (const float*)d_in[24];
  float* out = (float*)d_out;

  // workspace (float offsets), ~240.3 MB (same layout as R17/R19)
  float* ws    = (float*)d_ws;
  float* inp   = ws;                       // [65536][96] fp32 (later cand)
  u16*   inpb  = (u16*)(ws + 6291456);     // [65536][96] bf16 (later candb)
  float* t12   = ws + 9437184;             // [2048][6144] fp32; Zbuf overlays;
                                           //   also L2-partials P[3][1M] at init
  u16*   Zbuf  = (u16*)t12;                //   gate [65536][384] bf16 (exact fit)
  u16*   Wbuf  = (u16*)(ws + 22020096);    // update Wt [1024][64][288] bf16
  u16*   Wbuf128 = Wbuf;                   // gate Wt [1024][128][288] bf16 (overlay)
  u16*   Btp   = (u16*)(ws + 31457280);    // [6144][1024] bf16
  u16*   Zt    = Wbuf;                     // overlay Wbuf+Btp: [24576][1024]
  float* acc1  = ws + 34603008;            // [n,b,128]
  float* acc0  = ws + 42991616;            // [n,b,128]
  u16*   LbStk = (u16*)(ws + 51380224);    // [2048][1024] bf16 (Lhi ; L2)
  u16*   chebb = (u16*)(ws + 52428800);    // [3][1024][1024] bf16
  float* s12   = ws + 54001664;
  float* s12u  = ws + 54001792;
  float* part0 = ws + 54001920;            // [64][16][128]
  float* part1 = ws + 54132992;
  float* rbuf  = ws + 54264064;            // [n,b,64]
  u16*   Vbg   = (u16*)(ws + 58458368);    // [384][96] = 18432 fl
  float* bag   = ws + 58476800;            // [384]
  u16*   Vbu   = (u16*)(ws + 58477184);    // [256][96] = 12288 fl
  float* bau   = ws + 58489472;            // [256]
  u16*   LhiT  = (u16*)(ws + 58489728);    // [1024][1024] bf16
  u16*   LloT  = (u16*)(ws + 59014016);    // [1024][1024] bf16
  u16*   Llo   = (u16*)(ws + 59538304);    // [1024][1024] bf16  (end 60,062,592)
  float* wpTg  = ws + 58489728;            // overlay LhiT+ (dead after l2p)
  float* wpTu  = ws + 59079552;

  dim3 blk(256);
  dim3 blk512(512);

  // ---- init ----
  split_hilo<<<1024, blk, 0, stream>>>(Ltil, LbStk, Llo, 262144);
  transpose_split<<<dim3(32, 32), blk, 0, stream>>>(Ltil, LhiT, LloT);
  mfma_l2p<<<dim3(16, 16, 3), blk, 0, stream>>>(LbStk, Llo, LhiT, LloT, t12);
  wpool_tr<<<dim3(9, 4, 16), blk, 0, stream>>>(g_wpool, wpTg, 128);
  wpool_tr<<<dim3(9, 2, 16), blk, 0, stream>>>(u_wpool, wpTu, 64);
  l2_finish<<<1024, blk, 0, stream>>>(t12, LbStk + 1048576);
  conv_f2b<<<3072, blk, 0, stream>>>(cheb, chebb, 786432);

  // ---- gate AVWGCN (dim_out = 128) ----
  concat_bf2<<<24576, blk, 0, stream>>>(x, state, inp, inpb);
  transpose_b2b<<<dim3(3, 32, 64), blk, 0, stream>>>(inpb, 96, 96, Btp);
  mfma_stack8<<<dim3(48, 16), blk512, 0, stream>>>(LbStk, Btp, t12, 6144);
  vgen2<128, 7><<<384, dim3(128), 0, stream>>>(g_gw, g_iw, g_ib, 384, Vbg, bag);
  weightgen5<36864><<<dim3(144, 16), blk, 0, stream>>>(emb, wpTg, Wbuf128);
  pernode10<128><<<1024, blk, 0, stream>>>(inp, t12, Wbuf128, emb, g_bpool, acc0);
  zgemm<<<dim3(3, 512), blk, 0, stream>>>(inpb, Vbg, bag, Zbuf, 384);   // overlays t12 (dead)
  transpose_b2b<<<dim3(12, 32, 64), blk, 0, stream>>>(Zbuf, 384, 384, Zt);  // kills Wbuf/Btp
  mfma_k3<<<dim3(64, 8), blk512, 0, stream>>>(chebb, Zt, g_gb, acc1, 8192, 7);
  att_reduce<128><<<dim3(16, 64), blk, 0, stream>>>(acc0, acc1, part0, part1);
  att_finish<128, 8><<<64, blk, 0, stream>>>(part0, part1, g_a1w1, g_a1w2, g_a2w1, g_a2w2, s12);
  gate_combine_b2<<<16384, blk, 0, stream>>>(acc0, acc1, s12, x, state, inp, inpb, rbuf);

  // ---- update AVWGCN (dim_out = 64), input = cand/candb ----
  transpose_b2b<<<dim3(3, 32, 64), blk, 0, stream>>>(inpb, 96, 96, Btp);
  mfma_stack8<<<dim3(48, 16), blk512, 0, stream>>>(LbStk, Btp, t12, 6144);
  vgen2<64, 6><<<256, dim3(128), 0, stream>>>(u_gw, u_iw, u_ib, 192, Vbu, bau);
  weightgen5<18432><<<dim3(72, 16), blk, 0, stream>>>(emb, wpTu, Wbuf);
  pernode10<64><<<1024, blk, 0, stream>>>(inp, t12, Wbuf, emb, u_bpool, acc0);
  zgemm<<<dim3(2, 512), blk, 0, stream>>>(inpb, Vbu, bau, Zbuf, 256);
  transpose_b2b<<<dim3(6, 32, 64), blk, 0, stream>>>(Zbuf, 256, 192, Zt);
  mfma_k3<<<dim3(32, 8), blk512, 0, stream>>>(chebb, Zt, u_gb, acc1, 4096, 6);
  att_reduce<64><<<dim3(16, 64), blk, 0, stream>>>(acc0, acc1, part0, part1);
  att_finish<64, 4><<<64, blk, 0, stream>>>(part0, part1, u_a1w1, u_a1w2, u_a2w1, u_a2w2, s12u);
  final_h<<<16384, blk, 0, stream>>>(acc0, acc1, s12u, rbuf, state, out);
}

// Round 13
// 611.322 us; speedup vs baseline: 1.0482x; 1.0079x over previous
//
#include <hip/hip_runtime.h>
#include <hip/hip_bf16.h>
#include <math.h>

// RGSLCell on MI355X. R21 = R20 + update cheb GEMM occupancy fix:
//  Update mfma_k3 was the last GEMM at 1 block/CU (grid (32,8)=256 blocks).
//  R19/R20 established 2 blocks/CU wins for the 2-barrier structure. R21:
//  mfma_k3u = 128(M)x64(N), 8 waves 4x2 (32x32 each, acc[2][2] - the proven
//  mfma_l2p wave geometry), BK=64, 48KB LDS, 3 gloads/thread -> vmcnt(3).
//  Grid (64,8)=512 blocks = 2/CU. A re-fetch doubles but A3 (6MB) is
//  L2-resident. Same staging swizzle + ascending K-chain -> bit-identical.
//  Gate keeps the 58us mfma_k3 at (64,8) untouched.
// Everything else identical to R20 (616.1us, absmax 0.078125).

#define B_  64
#define N_  1024
#define CIN_ 96
#define R_  288

typedef __attribute__((ext_vector_type(8))) short bf16x8;
typedef __attribute__((ext_vector_type(4))) float f32x4;
typedef unsigned short u16;
typedef unsigned int u32;

__device__ __forceinline__ float lrelu(float v) { return v >= 0.f ? v : 0.01f * v; }
__device__ __forceinline__ float sigmoidf_(float u) { return 1.f / (1.f + expf(-u)); }
// round-to-nearest-even fp32 -> bf16
__device__ __forceinline__ u16 f2b(float f) {
  union { float f; u32 u; } c; c.f = f;
  u32 u = c.u;
  return (u16)((u + 0x7FFFu + ((u >> 16) & 1u)) >> 16);
}
__device__ __forceinline__ float b2f(u16 u) {
  union { u32 x; float f; } c; c.x = ((u32)u) << 16; return c.f;
}
__device__ __forceinline__ void gload_lds16(const u16* gp, u16* lp) {
  __builtin_amdgcn_global_load_lds((const __attribute__((address_space(1))) u32*)gp,
                                   (__attribute__((address_space(3))) u32*)lp, 16, 0, 0);
}

// ---------------------------------------------------------------------------
// concat: inp fp32 AND inpb bf16, layout [(n*64+b)][96]
__global__ __launch_bounds__(256) void concat_bf2(const float* __restrict__ x,
                                                  const float* __restrict__ st,
                                                  float* __restrict__ inp,
                                                  u16* __restrict__ inpb) {
  size_t t = (size_t)blockIdx.x * 256 + threadIdx.x;
  if (t >= (size_t)B_ * N_ * CIN_) return;
  int i = (int)(t % CIN_);
  size_t v = t / CIN_;
  size_t b = v & 63, n = v >> 6;
  float f = (i < 32) ? x[(b * N_ + n) * 32 + i] : st[(b * N_ + n) * 64 + (i - 32)];
  inp[t] = f;
  inpb[t] = f2b(f);
}

// fp32 -> bf16 flat convert (cheb)
__global__ __launch_bounds__(256) void conv_f2b(const float* __restrict__ in,
                                                u16* __restrict__ out, int n4) {
  int t = blockIdx.x * 256 + threadIdx.x;
  if (t >= n4) return;
  float4 v = ((const float4*)in)[t];
  ushort4 o;
  o.x = f2b(v.x); o.y = f2b(v.y); o.z = f2b(v.z); o.w = f2b(v.w);
  ((ushort4*)out)[t] = o;
}

// split fp32 -> (hi, lo) bf16 planes
__global__ __launch_bounds__(256) void split_hilo(const float* __restrict__ in,
                                                  u16* __restrict__ hi,
                                                  u16* __restrict__ lo, int n4) {
  int t = blockIdx.x * 256 + threadIdx.x;
  if (t >= n4) return;
  float4 v = ((const float4*)in)[t];
  ushort4 h, l;
  h.x = f2b(v.x); l.x = f2b(v.x - b2f(h.x));
  h.y = f2b(v.y); l.y = f2b(v.y - b2f(h.y));
  h.z = f2b(v.z); l.z = f2b(v.z - b2f(h.z));
  h.w = f2b(v.w); l.w = f2b(v.w - b2f(h.w));
  ((ushort4*)hi)[t] = h;
  ((ushort4*)lo)[t] = l;
}

// transpose fp32 [1024][1024] -> (hiT, loT) bf16 planes of L^T
__global__ __launch_bounds__(256) void transpose_split(const float* __restrict__ in,
                                                       u16* __restrict__ hiT,
                                                       u16* __restrict__ loT) {
  __shared__ float t[32][33];
  const int tid = threadIdx.x;
  const int j0 = blockIdx.x * 32, r0 = blockIdx.y * 32;
  const int tc = tid & 31, tr = tid >> 5;
#pragma unroll
  for (int q = 0; q < 4; ++q)
    t[tr + q * 8][tc] = in[(size_t)(r0 + tr + q * 8) * 1024 + j0 + tc];
  __syncthreads();
  const int jj = tid >> 3, rq = (tid & 7) * 4;
  ushort4 h, l;
#pragma unroll
  for (int q = 0; q < 4; ++q) {
    float v = t[rq + q][jj];
    u16 hh = f2b(v);
    ((u16*)&h)[q] = hh;
    ((u16*)&l)[q] = f2b(v - b2f(hh));
  }
  *(ushort4*)(hiT + (size_t)(j0 + jj) * N_ + r0 + rq) = h;
  *(ushort4*)(loT + (size_t)(j0 + jj) * N_ + r0 + rq) = l;
}

// transpose bf16 [(n*64+b)][Zs] -> bf16 [(b*Ctot+c)][1024]
__global__ __launch_bounds__(256) void transpose_b2b(const u16* __restrict__ Z, int Zs,
                                                     int Ctot, u16* __restrict__ Zt) {
  __shared__ u16 t[32][36];
  const int tid = threadIdx.x;
  const int c0 = blockIdx.x * 32, n0 = blockIdx.y * 32, b = blockIdx.z;
  {
    const int i = tid >> 3, c4 = (tid & 7) * 4;
    ushort4 v = *(const ushort4*)(Z + ((size_t)(n0 + i) * 64 + b) * Zs + c0 + c4);
    t[i][c4] = v.x; t[i][c4 + 1] = v.y; t[i][c4 + 2] = v.z; t[i][c4 + 3] = v.w;
  }
  __syncthreads();
  {
    const int c = tid >> 3, n4 = (tid & 7) * 4;
    ushort4 o;
    o.x = t[n4][c]; o.y = t[n4 + 1][c]; o.z = t[n4 + 2][c]; o.w = t[n4 + 3][c];
    *(ushort4*)(Zt + (size_t)(b * Ctot + c0 + c) * 1024 + n0 + n4) = o;
  }
}

// wpool transpose: wpT[d][o][r] = wp[d][r][o]. grid (288/32, OW/32, 16).
__global__ __launch_bounds__(256) void wpool_tr(const float* __restrict__ wp,
                                                float* __restrict__ wpT, int OW) {
  __shared__ float t[32][33];
  const int tid = threadIdx.x;
  const int r0 = blockIdx.x * 32, o0 = blockIdx.y * 32, d = blockIdx.z;
  const size_t base = (size_t)d * 288 * OW;
  const int c = tid & 31, q0 = tid >> 5;
#pragma unroll
  for (int q = 0; q < 4; ++q)
    t[q0 + q * 8][c] = wp[base + (size_t)(r0 + q0 + q * 8) * OW + o0 + c];
  __syncthreads();
#pragma unroll
  for (int q = 0; q < 4; ++q)
    wpT[base + (size_t)(o0 + q0 + q * 8) * 288 + r0 + c] = t[c][q0 + q * 8];
}

// ---------------------------------------------------------------------------
// compensated L2, phase-split: P[z] = (z==0 ? Lhi@Lhi : z==1 ? Llo@Lhi : Lhi@Llo)
__global__ __launch_bounds__(256) void mfma_l2p(const u16* __restrict__ Lhi,
                                                const u16* __restrict__ Llo,
                                                const u16* __restrict__ LhiT,
                                                const u16* __restrict__ LloT,
                                                float* __restrict__ P) {
  __shared__ u16 Asl[64 * 64];
  __shared__ u16 Bsl[64 * 64];
  const int tid = threadIdx.x;
  const int w = tid >> 6, lane = tid & 63;
  const int m0 = blockIdx.y * 64, n0 = blockIdx.x * 64;
  const int ph = blockIdx.z;
  const int wr = w >> 1, wc = w & 1;
  const int sr = lane >> 3, so = lane & 7;
  const int cl = lane & 15, q4 = lane >> 4;
  f32x4 acc[2][2] = {};

  const u16* A = (ph == 1) ? Llo : Lhi;
  const u16* B = (ph == 2) ? LloT : LhiT;
  for (int k0 = 0; k0 < 1024; k0 += 64) {
    __syncthreads();
#pragma unroll
    for (int i = 0; i < 2; ++i) {
      const int r = i * 32 + w * 8 + sr;
      const int o = so ^ (r & 7);
      gload_lds16(A + (size_t)(m0 + r) * 1024 + k0 + o * 8, Asl + (i * 32 + w * 8) * 64);
      gload_lds16(B + (size_t)(n0 + r) * 1024 + k0 + o * 8, Bsl + (i * 32 + w * 8) * 64);
    }
    __syncthreads();
#pragma unroll
    for (int kk = 0; kk < 2; ++kk) {
      bf16x8 af[2], bfr[2];
#pragma unroll
      for (int mi = 0; mi < 2; ++mi) {
        const int ra = wr * 32 + mi * 16 + cl;
        af[mi] = *(const bf16x8*)(Asl + ra * 64 + ((kk * 4 + q4) ^ (ra & 7)) * 8);
      }
#pragma unroll
      for (int ni = 0; ni < 2; ++ni) {
        const int rb = wc * 32 + ni * 16 + cl;
        bfr[ni] = *(const bf16x8*)(Bsl + rb * 64 + ((kk * 4 + q4) ^ (rb & 7)) * 8);
      }
#pragma unroll
      for (int mi = 0; mi < 2; ++mi)
#pragma unroll
        for (int ni = 0; ni < 2; ++ni)
          acc[mi][ni] = __builtin_amdgcn_mfma_f32_16x16x32_bf16(af[mi], bfr[ni], acc[mi][ni], 0, 0, 0);
    }
  }
  float* Pz = P + ((size_t)ph << 20);
#pragma unroll
  for (int mi = 0; mi < 2; ++mi)
#pragma unroll
    for (int ni = 0; ni < 2; ++ni) {
      const int j = n0 + wc * 32 + ni * 16 + cl;
#pragma unroll
      for (int r = 0; r < 4; ++r) {
        const int m = m0 + wr * 32 + mi * 16 + q4 * 4 + r;
        Pz[(size_t)m * 1024 + j] = acc[mi][ni][r];
      }
    }
}

// combine the 3 partials: Y = bf16(2*(P0+P1+P2) - I)
__global__ __launch_bounds__(256) void l2_finish(const float* __restrict__ P,
                                                 u16* __restrict__ Y) {
  int t = blockIdx.x * 256 + threadIdx.x;   // 262144 float4 groups
  float4 a = ((const float4*)P)[t];
  float4 b = ((const float4*)(P + 1048576))[t];
  float4 c = ((const float4*)(P + 2097152))[t];
  int e = t << 2;
  int m = e >> 10, j = e & 1023;
  ushort4 o;
  o.x = f2b(2.f * (a.x + b.x + c.x) - (m == j     ? 1.f : 0.f));
  o.y = f2b(2.f * (a.y + b.y + c.y) - (m == j + 1 ? 1.f : 0.f));
  o.z = f2b(2.f * (a.z + b.z + c.z) - (m == j + 2 ? 1.f : 0.f));
  o.w = f2b(2.f * (a.w + b.w + c.w) - (m == j + 3 ? 1.f : 0.f));
  ((ushort4*)Y)[t] = o;
}

// ---------------------------------------------------------------------------
// stack GEMM (R20): Y[2048][J] = A@B, 128x128 tile, 8 waves (2x4), acc[4][2],
// BK=64, 64KB LDS, counted vmcnt(4). Grid (J/128, 16) = 768 blocks.
__global__ __launch_bounds__(512) void mfma_stack8(const u16* __restrict__ A,
                                                   const u16* __restrict__ Bt,
                                                   float* __restrict__ Y, int J) {
  __shared__ u16 Asl[2][128 * 64];
  __shared__ u16 Bsl[2][128 * 64];
  const int tid = threadIdx.x;
  const int w = tid >> 6, lane = tid & 63;    // w 0..7
  const int m0 = blockIdx.y * 128, n0 = blockIdx.x * 128;
  const int wr = w >> 2, wc = w & 3;          // wr 0..1, wc 0..3
  const int sr = lane >> 3, so = lane & 7;
  const int cl = lane & 15, q4 = lane >> 4;
  f32x4 acc[4][2] = {};

  auto STAGE = [&](u16* Ad, u16* Bd, int k0) {
#pragma unroll
    for (int i = 0; i < 2; ++i) {
      const int r = i * 64 + w * 8 + sr;
      const int o = so ^ (r & 7);
      gload_lds16(A + (size_t)(m0 + r) * 1024 + k0 + o * 8, Ad + (i * 64 + w * 8) * 64);
      gload_lds16(Bt + (size_t)(n0 + r) * 1024 + k0 + o * 8, Bd + (i * 64 + w * 8) * 64);
    }
  };
  auto COMPUTE = [&](const u16* As, const u16* Bs) {
#pragma unroll
    for (int kk = 0; kk < 2; ++kk) {
      bf16x8 af[4], bfr[2];
#pragma unroll
      for (int mi = 0; mi < 4; ++mi) {
        const int ra = wr * 64 + mi * 16 + cl;
        af[mi] = *(const bf16x8*)(As + ra * 64 + ((kk * 4 + q4) ^ (ra & 7)) * 8);
      }
#pragma unroll
      for (int ni = 0; ni < 2; ++ni) {
        const int rb = wc * 32 + ni * 16 + cl;
        bfr[ni] = *(const bf16x8*)(Bs + rb * 64 + ((kk * 4 + q4) ^ (rb & 7)) * 8);
      }
#pragma unroll
      for (int mi = 0; mi < 4; ++mi)
#pragma unroll
        for (int ni = 0; ni < 2; ++ni)
          acc[mi][ni] = __builtin_amdgcn_mfma_f32_16x16x32_bf16(af[mi], bfr[ni], acc[mi][ni], 0, 0, 0);
    }
  };

  STAGE(Asl[0], Bsl[0], 0);
  for (int k0 = 0; k0 < 1024; k0 += 128) {
    STAGE(Asl[1], Bsl[1], k0 + 64);
    asm volatile("s_waitcnt vmcnt(4)" ::: "memory");
    __builtin_amdgcn_s_barrier();
    __builtin_amdgcn_sched_barrier(0);
    COMPUTE(Asl[0], Bsl[0]);
    asm volatile("s_waitcnt lgkmcnt(0)" ::: "memory");
    __builtin_amdgcn_s_barrier();
    __builtin_amdgcn_sched_barrier(0);
    if (k0 + 128 < 1024) {
      STAGE(Asl[0], Bsl[0], k0 + 128);
      asm volatile("s_waitcnt vmcnt(4)" ::: "memory");
    } else {
      asm volatile("s_waitcnt vmcnt(0)" ::: "memory");
    }
    __builtin_amdgcn_s_barrier();
    __builtin_amdgcn_sched_barrier(0);
    COMPUTE(Asl[1], Bsl[1]);
    asm volatile("s_waitcnt lgkmcnt(0)" ::: "memory");
    __builtin_amdgcn_s_barrier();
    __builtin_amdgcn_sched_barrier(0);
  }
#pragma unroll
  for (int mi = 0; mi < 4; ++mi)
#pragma unroll
    for (int ni = 0; ni < 2; ++ni) {
      const int j = n0 + wc * 32 + ni * 16 + cl;
#pragma unroll
      for (int r = 0; r < 4; ++r) {
        const int m = m0 + wr * 64 + mi * 16 + q4 * 4 + r;
        Y[(size_t)m * J + j] = acc[mi][ni][r];
      }
    }
}

// ---------------------------------------------------------------------------
// vgen2: one block per output row c.
template <int O, int OSH>
__global__ __launch_bounds__(128) void vgen2(const float* __restrict__ gw,
                                             const float* __restrict__ iw,
                                             const float* __restrict__ ib,
                                             int Ctot,
                                             u16* __restrict__ Vb,
                                             float* __restrict__ ball) {
  const int c = blockIdx.x;
  const int col = threadIdx.x;
  if (c >= Ctot) {  // zero-pad (block-uniform branch)
    if (col < 96) Vb[(size_t)c * 96 + col] = 0;
    else if (col == 96) ball[c] = 0.f;
    return;
  }
  __shared__ float sg[O];
  const int o = c & (O - 1), k = c >> OSH;
  const float* g = gw + (size_t)o * (3 * O) + (size_t)k * O;
  for (int e = col; e < O; e += 128) sg[e] = g[e];
  __syncthreads();
  if (col < 96) {
    float s = 0.f;
#pragma unroll
    for (int j = 0; j < O; ++j) s += sg[j] * iw[j * 96 + col];
    Vb[(size_t)c * 96 + col] = f2b(s);
  } else if (col == 96) {
    float s = 0.f;
#pragma unroll
    for (int j = 0; j < O; ++j) s += sg[j] * ib[j];
    ball[c] = s;
  }
}

// ---------------------------------------------------------------------------
// zgemm: Z[M][Zs] bf16 = A[M][96] @ Vb^T + ball. 128x128 tile, BK=32 x 3.
__global__ __launch_bounds__(256) void zgemm(const u16* __restrict__ A,
                                             const u16* __restrict__ Bt,
                                             const float* __restrict__ ball,
                                             u16* __restrict__ Z, int Zs) {
  __shared__ u16 Asl[128 * 32];
  __shared__ u16 Bsl[128 * 32];
  const int tid = threadIdx.x;
  const int w = tid >> 6, lane = tid & 63;
  const int m0 = blockIdx.y * 128, n0 = blockIdx.x * 128;
  const int wr = w >> 1, wc = w & 1;
  const int sr = lane >> 2, so = lane & 3;
  const int cl = lane & 15, q4 = lane >> 4;
  f32x4 acc[4][4] = {};
  for (int k0 = 0; k0 < 96; k0 += 32) {
    __syncthreads();
#pragma unroll
    for (int i = 0; i < 2; ++i) {
      const int r = i * 64 + w * 16 + sr;
      const int o = so ^ (r & 3);
      gload_lds16(A + (size_t)(m0 + r) * 96 + k0 + o * 8, Asl + (i * 64 + w * 16) * 32);
      gload_lds16(Bt + (size_t)(n0 + r) * 96 + k0 + o * 8, Bsl + (i * 64 + w * 16) * 32);
    }
    __syncthreads();
    bf16x8 af[4], bfr[4];
#pragma unroll
    for (int mi = 0; mi < 4; ++mi) {
      const int ra = wr * 64 + mi * 16 + cl;
      af[mi] = *(const bf16x8*)(Asl + ra * 32 + (q4 ^ (ra & 3)) * 8);
    }
#pragma unroll
    for (int ni = 0; ni < 4; ++ni) {
      const int rb = wc * 64 + ni * 16 + cl;
      bfr[ni] = *(const bf16x8*)(Bsl + rb * 32 + (q4 ^ (rb & 3)) * 8);
    }
#pragma unroll
    for (int mi = 0; mi < 4; ++mi)
#pragma unroll
      for (int ni = 0; ni < 4; ++ni)
        acc[mi][ni] = __builtin_amdgcn_mfma_f32_16x16x32_bf16(af[mi], bfr[ni], acc[mi][ni], 0, 0, 0);
  }
#pragma unroll
  for (int mi = 0; mi < 4; ++mi)
#pragma unroll
    for (int ni = 0; ni < 4; ++ni) {
      const int c = n0 + wc * 64 + ni * 16 + cl;
      const float bb = ball[c];
#pragma unroll
      for (int r = 0; r < 4; ++r) {
        const int m = m0 + wr * 64 + mi * 16 + q4 * 4 + r;
        Z[(size_t)m * Zs + c] = f2b(acc[mi][ni][r] + bb);
      }
    }
}

// ---------------------------------------------------------------------------
// stacked-K cheb GEMM (GATE): 128x128, 8 waves (2x4), acc[4][2], BK=64.
// Grid (64,8) = 512 blocks = 2 blocks/CU. R11/R19-proven 58us.
__global__ __launch_bounds__(512) void mfma_k3(const u16* __restrict__ A3,
                                               const u16* __restrict__ Zt,
                                               const float* __restrict__ gb,
                                               float* __restrict__ Y,
                                               int J, int obits) {
  __shared__ u16 Asl[2][128 * 64];
  __shared__ u16 Bsl[2][128 * 64];
  const int tid = threadIdx.x;
  const int w = tid >> 6, lane = tid & 63;    // w 0..7
  const int m0 = blockIdx.y * 128, n0 = blockIdx.x * 128;
  const int wr = w >> 2, wc = w & 3;          // wr 0..1, wc 0..3
  const int sr = lane >> 3, so = lane & 7;
  const int cl = lane & 15, q4 = lane >> 4;
  const int omask = (1 << obits) - 1;
  f32x4 acc[4][2] = {};

  auto STAGE = [&](u16* Ad, u16* Bd, int k0) {
    const int kb = k0 >> 10, ko = k0 & 1023;
#pragma unroll
    for (int i = 0; i < 2; ++i) {
      const int r = i * 64 + w * 8 + sr;
      const int o = so ^ (r & 7);
      gload_lds16(A3 + (size_t)kb * 1048576 + (size_t)(m0 + r) * 1024 + ko + o * 8,
                  Ad + (i * 64 + w * 8) * 64);
      const int jp = n0 + r;
      const int brow = (((jp >> obits) * 3 + kb) << obits) | (jp & omask);
      gload_lds16(Zt + (size_t)brow * 1024 + ko + o * 8, Bd + (i * 64 + w * 8) * 64);
    }
  };
  auto COMPUTE = [&](const u16* As, const u16* Bs) {
#pragma unroll
    for (int kk = 0; kk < 2; ++kk) {
      bf16x8 af[4], bfr[2];
#pragma unroll
      for (int mi = 0; mi < 4; ++mi) {
        const int ra = wr * 64 + mi * 16 + cl;
        af[mi] = *(const bf16x8*)(As + ra * 64 + ((kk * 4 + q4) ^ (ra & 7)) * 8);
      }
#pragma unroll
      for (int ni = 0; ni < 2; ++ni) {
        const int rb = wc * 32 + ni * 16 + cl;
        bfr[ni] = *(const bf16x8*)(Bs + rb * 64 + ((kk * 4 + q4) ^ (rb & 7)) * 8);
      }
#pragma unroll
      for (int mi = 0; mi < 4; ++mi)
#pragma unroll
        for (int ni = 0; ni < 2; ++ni)
          acc[mi][ni] = __builtin_amdgcn_mfma_f32_16x16x32_bf16(af[mi], bfr[ni], acc[mi][ni], 0, 0, 0);
    }
  };

  STAGE(Asl[0], Bsl[0], 0);
  for (int k0 = 0; k0 < 3072; k0 += 128) {
    STAGE(Asl[1], Bsl[1], k0 + 64);
    asm volatile("s_waitcnt vmcnt(4)" ::: "memory");
    __builtin_amdgcn_s_barrier();
    __builtin_amdgcn_sched_barrier(0);
    COMPUTE(Asl[0], Bsl[0]);
    asm volatile("s_waitcnt lgkmcnt(0)" ::: "memory");
    __builtin_amdgcn_s_barrier();
    __builtin_amdgcn_sched_barrier(0);
    if (k0 + 128 < 3072) {
      STAGE(Asl[0], Bsl[0], k0 + 128);
      asm volatile("s_waitcnt vmcnt(4)" ::: "memory");
    } else {
      asm volatile("s_waitcnt vmcnt(0)" ::: "memory");
    }
    __builtin_amdgcn_s_barrier();
    __builtin_amdgcn_sched_barrier(0);
    COMPUTE(Asl[1], Bsl[1]);
    asm volatile("s_waitcnt lgkmcnt(0)" ::: "memory");
    __builtin_amdgcn_s_barrier();
    __builtin_amdgcn_sched_barrier(0);
  }
#pragma unroll
  for (int mi = 0; mi < 4; ++mi)
#pragma unroll
    for (int ni = 0; ni < 2; ++ni) {
      const int j = n0 + wc * 32 + ni * 16 + cl;
      const float bb = gb[j & omask];
#pragma unroll
      for (int r = 0; r < 4; ++r) {
        const int m = m0 + wr * 64 + mi * 16 + q4 * 4 + r;
        Y[(size_t)m * J + j] = acc[mi][ni][r] + bb;
      }
    }
}

// ---------------------------------------------------------------------------
// R21: stacked-K cheb GEMM (UPDATE): 128(M)x64(N), 8 waves 4x2 (32x32 each,
// acc[2][2] - mfma_l2p wave geometry), BK=64, 48KB LDS, 3 gloads/thread ->
// counted vmcnt(3). Grid (J/64=64, 8) = 512 blocks = 2 blocks/CU.
__global__ __launch_bounds__(512) void mfma_k3u(const u16* __restrict__ A3,
                                                const u16* __restrict__ Zt,
                                                const float* __restrict__ gb,
                                                float* __restrict__ Y,
                                                int J, int obits) {
  __shared__ u16 Asl[2][128 * 64];
  __shared__ u16 Bsl[2][64 * 64];
  const int tid = threadIdx.x;
  const int w = tid >> 6, lane = tid & 63;    // w 0..7
  const int m0 = blockIdx.y * 128, n0 = blockIdx.x * 64;
  const int wr = w >> 1, wc = w & 1;          // wr 0..3 (32 rows), wc 0..1 (32 cols)
  const int sr = lane >> 3, so = lane & 7;
  const int cl = lane & 15, q4 = lane >> 4;
  const int omask = (1 << obits) - 1;
  f32x4 acc[2][2] = {};

  auto STAGE = [&](u16* Ad, u16* Bd, int k0) {
    const int kb = k0 >> 10, ko = k0 & 1023;
#pragma unroll
    for (int i = 0; i < 2; ++i) {
      const int r = i * 64 + w * 8 + sr;
      const int o = so ^ (r & 7);
      gload_lds16(A3 + (size_t)kb * 1048576 + (size_t)(m0 + r) * 1024 + ko + o * 8,
                  Ad + (i * 64 + w * 8) * 64);
    }
    {
      const int r = w * 8 + sr;                // B: 64 rows, 1 load/thread
      const int o = so ^ (r & 7);
      const int jp = n0 + r;
      const int brow = (((jp >> obits) * 3 + kb) << obits) | (jp & omask);
      gload_lds16(Zt + (size_t)brow * 1024 + ko + o * 8, Bd + (w * 8) * 64);
    }
  };
  auto COMPUTE = [&](const u16* As, const u16* Bs) {
#pragma unroll
    for (int kk = 0; kk < 2; ++kk) {
      bf16x8 af[2], bfr[2];
#pragma unroll
      for (int mi = 0; mi < 2; ++mi) {
        const int ra = wr * 32 + mi * 16 + cl;
        af[mi] = *(const bf16x8*)(As + ra * 64 + ((kk * 4 + q4) ^ (ra & 7)) * 8);
      }
#pragma unroll
      for (int ni = 0; ni < 2; ++ni) {
        const int rb = wc * 32 + ni * 16 + cl;
        bfr[ni] = *(const bf16x8*)(Bs + rb * 64 + ((kk * 4 + q4) ^ (rb & 7)) * 8);
      }
#pragma unroll
      for (int mi = 0; mi < 2; ++mi)
#pragma unroll
        for (int ni = 0; ni < 2; ++ni)
          acc[mi][ni] = __builtin_amdgcn_mfma_f32_16x16x32_bf16(af[mi], bfr[ni], acc[mi][ni], 0, 0, 0);
    }
  };

  STAGE(Asl[0], Bsl[0], 0);
  for (int k0 = 0; k0 < 3072; k0 += 128) {
    STAGE(Asl[1], Bsl[1], k0 + 64);
    asm volatile("s_waitcnt vmcnt(3)" ::: "memory");
    __builtin_amdgcn_s_barrier();
    __builtin_amdgcn_sched_barrier(0);
    COMPUTE(Asl[0], Bsl[0]);
    asm volatile("s_waitcnt lgkmcnt(0)" ::: "memory");
    __builtin_amdgcn_s_barrier();
    __builtin_amdgcn_sched_barrier(0);
    if (k0 + 128 < 3072) {
      STAGE(Asl[0], Bsl[0], k0 + 128);
      asm volatile("s_waitcnt vmcnt(3)" ::: "memory");
    } else {
      asm volatile("s_waitcnt vmcnt(0)" ::: "memory");
    }
    __builtin_amdgcn_s_barrier();
    __builtin_amdgcn_sched_barrier(0);
    COMPUTE(Asl[1], Bsl[1]);
    asm volatile("s_waitcnt lgkmcnt(0)" ::: "memory");
    __builtin_amdgcn_s_barrier();
    __builtin_amdgcn_sched_barrier(0);
  }
#pragma unroll
  for (int mi = 0; mi < 2; ++mi)
#pragma unroll
    for (int ni = 0; ni < 2; ++ni) {
      const int j = n0 + wc * 32 + ni * 16 + cl;
      const float bb = gb[j & omask];
#pragma unroll
      for (int r = 0; r < 4; ++r) {
        const int m = m0 + wr * 32 + mi * 16 + q4 * 4 + r;
        Y[(size_t)m * J + j] = acc[mi][ni][r] + bb;
      }
    }
}

// ---------------------------------------------------------------------------
// weightgen5: Wt[n][SZ] bf16 = sum_d emb[n][d]*wpoolT[d][SZ] (linear; SZ=OW*288)
template <int SZ>
__global__ __launch_bounds__(256) void weightgen5(const float* __restrict__ emb,
                                                  const float* __restrict__ wpT,
                                                  u16* __restrict__ W) {
  const int tid = threadIdx.x;
  const int ro = blockIdx.x * 256 + tid;
  const int n0 = blockIdx.y * 64;
  __shared__ float semb[64][17];
  for (int e = tid; e < 1024; e += 256) semb[e >> 4][e & 15] = emb[(n0 + (e >> 4)) * 16 + (e & 15)];
  __syncthreads();
  float wv[16];
#pragma unroll
  for (int d = 0; d < 16; ++d) wv[d] = wpT[(size_t)d * SZ + ro];
#pragma unroll 4
  for (int n = 0; n < 64; ++n) {
    float s = 0.f;
#pragma unroll
    for (int d = 0; d < 16; ++d) s += semb[n][d] * wv[d];
    W[(size_t)(n0 + n) * SZ + ro] = f2b(s);
  }
}

// pernode10: per-node GEMM on the MATRIX pipe. Block per node, 4 waves.
// C[o][b] = Wt[n] @ X^T. X fp32 -> hi/lo bf16 in LDS. 9 chunks x {hi,lo}.
template <int OW>
__global__ __launch_bounds__(256) void pernode10(const float* __restrict__ xa,
                                                 const float* __restrict__ xbc,
                                                 const u16* __restrict__ Wt,
                                                 const float* __restrict__ emb,
                                                 const float* __restrict__ bpool,
                                                 float* __restrict__ outp) {
  constexpr int MT = OW / 64;            // o 16-tiles per wave (2 gate, 1 upd)
  const int n = blockIdx.x;
  const int tid = threadIdx.x;
  const int w = tid >> 6, lane = tid & 63;
  const int cl = lane & 15, q4 = lane >> 4;
  __shared__ u16 sWt[OW * 32];
  __shared__ u16 sXh[64 * 32];
  __shared__ u16 sXl[64 * 32];
  __shared__ float semb[16];
  if (tid < 16) semb[tid] = emb[n * 16 + tid];
  f32x4 acc[MT][4] = {};
  const u16* Wn = Wt + (size_t)n * (OW * 288);
  const int xb = tid >> 2, rg = tid & 3;  // X staging map: b row, 8-r group

  for (int c = 0; c < 9; ++c) {
    const int k = c / 3, i0 = (c % 3) * 32;
    const float* xk = (k == 0) ? (xa + (size_t)n * 6144)
                               : (xbc + ((size_t)(k - 1) * 1024 + n) * 6144);
    __syncthreads();
#pragma unroll
    for (int i = 0; i < MT; ++i) {
      const int g = w * MT + i;                  // 16-row group
      const int o = g * 16 + (lane >> 2);
      const int seg = (lane & 3) ^ (o & 3);
      gload_lds16(Wn + (size_t)o * 288 + c * 32 + seg * 8, sWt + g * 512);
    }
    {
      const float* p = xk + (size_t)xb * 96 + i0 + rg * 8;
      float4 v0 = *(const float4*)p;
      float4 v1 = *(const float4*)(p + 4);
      float xv[8] = {v0.x, v0.y, v0.z, v0.w, v1.x, v1.y, v1.z, v1.w};
      bf16x8 h, l;
#pragma unroll
      for (int j = 0; j < 8; ++j) {
        u16 hh = f2b(xv[j]);
        ((u16*)&h)[j] = hh;
        ((u16*)&l)[j] = f2b(xv[j] - b2f(hh));
      }
      const int col = (rg ^ (xb & 3)) * 8;
      *(bf16x8*)(sXh + xb * 32 + col) = h;
      *(bf16x8*)(sXl + xb * 32 + col) = l;
    }
    __syncthreads();
    bf16x8 aw[MT], bh[4], bl[4];
#pragma unroll
    for (int mi = 0; mi < MT; ++mi) {
      const int o = (w * MT + mi) * 16 + cl;
      aw[mi] = *(const bf16x8*)(sWt + o * 32 + ((q4 ^ (o & 3)) * 8));
    }
#pragma unroll
    for (int ni = 0; ni < 4; ++ni) {
      const int b = ni * 16 + cl;
      const int col = (q4 ^ (b & 3)) * 8;
      bh[ni] = *(const bf16x8*)(sXh + b * 32 + col);
      bl[ni] = *(const bf16x8*)(sXl + b * 32 + col);
    }
#pragma unroll
    for (int mi = 0; mi < MT; ++mi)
#pragma unroll
      for (int ni = 0; ni < 4; ++ni)
        acc[mi][ni] = __builtin_amdgcn_mfma_f32_16x16x32_bf16(aw[mi], bh[ni], acc[mi][ni], 0, 0, 0);
#pragma unroll
    for (int mi = 0; mi < MT; ++mi)
#pragma unroll
      for (int ni = 0; ni < 4; ++ni)
        acc[mi][ni] = __builtin_amdgcn_mfma_f32_16x16x32_bf16(aw[mi], bl[ni], acc[mi][ni], 0, 0, 0);
  }
  float4 biasv[MT];
#pragma unroll
  for (int mi = 0; mi < MT; ++mi)
#pragma unroll
    for (int r = 0; r < 4; ++r) {
      const int o = (w * MT + mi) * 16 + q4 * 4 + r;
      float s = 0.f;
#pragma unroll
      for (int d = 0; d < 16; ++d) s += semb[d] * bpool[d * OW + o];
      ((float*)&biasv[mi])[r] = s;
    }
#pragma unroll
  for (int mi = 0; mi < MT; ++mi)
#pragma unroll
    for (int ni = 0; ni < 4; ++ni) {
      const int b = ni * 16 + cl;
      float4 v;
      v.x = acc[mi][ni][0] + biasv[mi].x;
      v.y = acc[mi][ni][1] + biasv[mi].y;
      v.z = acc[mi][ni][2] + biasv[mi].z;
      v.w = acc[mi][ni][3] + biasv[mi].w;
      *(float4*)(outp + ((size_t)n * 64 + b) * OW + (w * MT + mi) * 16 + q4 * 4) = v;
    }
}

// ---------------------------------------------------------------------------
// two-stage attention mean
template <int C>
__global__ __launch_bounds__(256) void att_reduce(const float* __restrict__ A0,
                                                  const float* __restrict__ A1,
                                                  float* __restrict__ part0,
                                                  float* __restrict__ part1) {
  constexpr int C4 = C / 4;
  constexpr int H = 256 / C4;
  const int chunk = blockIdx.x;
  const int b = blockIdx.y;
  const int tid = threadIdx.x;
  const int c4 = tid % C4, h = tid / C4;
  __shared__ float4 r0[256], r1[256];
  float4 s0 = {0.f, 0.f, 0.f, 0.f}, s1 = {0.f, 0.f, 0.f, 0.f};
  const float4* p0 = (const float4*)(A0 + (size_t)b * C) + c4;
  const float4* p1 = (const float4*)(A1 + (size_t)b * C) + c4;
  const size_t stride = (size_t)B_ * C4;
  for (int n = chunk * 64 + h; n < chunk * 64 + 64; n += H) {
    float4 v0 = p0[(size_t)n * stride];
    float4 v1 = p1[(size_t)n * stride];
    s0.x += lrelu(v0.x); s0.y += lrelu(v0.y); s0.z += lrelu(v0.z); s0.w += lrelu(v0.w);
    s1.x += lrelu(v1.x); s1.y += lrelu(v1.y); s1.z += lrelu(v1.z); s1.w += lrelu(v1.w);
  }
  r0[tid] = s0; r1[tid] = s1;
  __syncthreads();
  if (h == 0) {
    for (int hh = 1; hh < H; ++hh) {
      float4 a = r0[c4 + hh * C4], bb = r1[c4 + hh * C4];
      s0.x += a.x; s0.y += a.y; s0.z += a.z; s0.w += a.w;
      s1.x += bb.x; s1.y += bb.y; s1.z += bb.z; s1.w += bb.w;
    }
    ((float4*)(part0 + ((size_t)b * 16 + chunk) * C))[c4] = s0;
    ((float4*)(part1 + ((size_t)b * 16 + chunk) * C))[c4] = s1;
  }
}

template <int C, int HID>
__global__ __launch_bounds__(256) void att_finish(const float* __restrict__ part0,
                                                  const float* __restrict__ part1,
                                                  const float* __restrict__ w11,
                                                  const float* __restrict__ w12,
                                                  const float* __restrict__ w21,
                                                  const float* __restrict__ w22,
                                                  float* __restrict__ sout) {
  const int b = blockIdx.x;
  const int tid = threadIdx.x;
  __shared__ float sm0[C], sm1[C];
  __shared__ float h0[HID], h1[HID];
  if (tid < C) {
    float s0 = 0.f, s1 = 0.f;
    for (int ch = 0; ch < 16; ++ch) {
      s0 += part0[((size_t)b * 16 + ch) * C + tid];
      s1 += part1[((size_t)b * 16 + ch) * C + tid];
    }
    sm0[tid] = s0 * (1.f / N_); sm1[tid] = s1 * (1.f / N_);
  }
  __syncthreads();
  if (tid < HID) {
    float a = 0.f;
    for (int cc = 0; cc < C; ++cc) a += sm0[cc] * w11[tid * C + cc];
    h0[tid] = fmaxf(a, 0.f);
  } else if (tid >= 32 && tid < 32 + HID) {
    int j = tid - 32;
    float a = 0.f;
    for (int cc = 0; cc < C; ++cc) a += sm1[cc] * w21[j * C + cc];
    h1[j] = fmaxf(a, 0.f);
  }
  __syncthreads();
  if (tid == 0) {
    float a = 0.f;
    for (int j = 0; j < HID; ++j) a += h0[j] * w12[j];
    sout[b] = sigmoidf_(a);
  } else if (tid == 32) {
    float a = 0.f;
    for (int j = 0; j < HID; ++j) a += h1[j] * w22[j];
    sout[B_ + b] = sigmoidf_(a);
  }
}

// ---------------------------------------------------------------------------
// gate combine -> cand fp32 + candb bf16 + rbuf fp32
__global__ __launch_bounds__(256) void gate_combine_b2(const float* __restrict__ a0,
                                                       const float* __restrict__ a1,
                                                       const float* __restrict__ s12,
                                                       const float* __restrict__ x,
                                                       const float* __restrict__ st,
                                                       float* __restrict__ cand,
                                                       u16* __restrict__ candb,
                                                       float* __restrict__ rbuf) {
  size_t t = (size_t)blockIdx.x * 256 + threadIdx.x;
  if (t >= (size_t)B_ * N_ * 64) return;
  int c = (int)(t & 63);
  int b = (int)((t >> 6) & 63);
  int n = (int)(t >> 12);
  float s1 = s12[b], s2 = s12[B_ + b];
  size_t nb = (size_t)n * B_ + b;
  size_t i128 = nb * 128;
  float uz = s1 * lrelu(a0[i128 + c]) + s2 * lrelu(a1[i128 + c]);
  float ur = s1 * lrelu(a0[i128 + 64 + c]) + s2 * lrelu(a1[i128 + 64 + c]);
  float z = sigmoidf_(uz);
  float r = sigmoidf_(ur);
  float stv = st[((size_t)b * N_ + n) * 64 + c];
  float zs = z * stv;
  cand[nb * CIN_ + 32 + c] = zs;
  candb[nb * CIN_ + 32 + c] = f2b(zs);
  rbuf[nb * 64 + c] = r;
  if (c < 32) {
    float xv = x[((size_t)b * N_ + n) * 32 + c];
    cand[nb * CIN_ + c] = xv;
    candb[nb * CIN_ + c] = f2b(xv);
  }
}

__global__ __launch_bounds__(256) void final_h(const float* __restrict__ a0,
                                               const float* __restrict__ a1,
                                               const float* __restrict__ s12,
                                               const float* __restrict__ rbuf,
                                               const float* __restrict__ st,
                                               float* __restrict__ out) {
  size_t t = (size_t)blockIdx.x * 256 + threadIdx.x;
  if (t >= (size_t)B_ * N_ * 64) return;
  int o = (int)(t & 63);
  int n = (int)((t >> 6) & 1023);
  int b = (int)(t >> 16);
  float s1 = s12[b], s2 = s12[B_ + b];
  size_t nb = ((size_t)n * B_ + b) * 64 + o;
  float u = s1 * lrelu(a0[nb]) + s2 * lrelu(a1[nb]);
  float hc = tanhf(u);
  float r = rbuf[nb];
  out[t] = r * st[t] + (1.f - r) * hc;
}

// ---------------------------------------------------------------------------
extern "C" void kernel_launch(void* const* d_in, const int* in_sizes, int n_in,
                              void* d_out, int out_size, void* d_ws, size_t ws_size,
                              hipStream_t stream) {
  const float* x       = (const float*)d_in[0];
  const float* state   = (const float*)d_in[1];
  const float* emb     = (const float*)d_in[2];
  const float* Ltil    = (const float*)d_in[3];
  const float* cheb    = (const float*)d_in[4];
  const float* g_wpool = (const float*)d_in[5];
  const float* g_bpool = (const float*)d_in[6];
  const float* g_iw    = (const float*)d_in[7];
  const float* g_ib    = (const float*)d_in[8];
  const float* g_gw    = (const float*)d_in[9];
  const float* g_gb    = (const float*)d_in[10];
  const float* g_a1w1  = (const float*)d_in[11];
  const float* g_a1w2  = (const float*)d_in[12];
  const float* g_a2w1  = (const float*)d_in[13];
  const float* g_a2w2  = (const float*)d_in[14];
  const float* u_wpool = (const float*)d_in[15];
  const float* u_bpool = (const float*)d_in[16];
  const float* u_iw    = (const float*)d_in[17];
  const float* u_ib    = (const float*)d_in[18];
  const float* u_gw    = (const float*)d_in[19];
  const float* u_gb    = (const float*)d_in[20];
  const float* u_a1w1  = (const float*)d_in[21];
  const float* u_a1w2  = (const float*)d_in[22];
  const float* u_a2w1  = (const float*)d_in[23];
  const float* u_a2w2  = (const float*)d_in[24];
  float* out = (float*)d_out;

  // workspace (float offsets), ~240.3 MB (same layout as R17/R19/R20)
  float* ws    = (float*)d_ws;
  float* inp   = ws;                       // [65536][96] fp32 (later cand)
  u16*   inpb  = (u16*)(ws + 6291456);     // [65536][96] bf16 (later candb)
  float* t12   = ws + 9437184;             // [2048][6144] fp32; Zbuf overlays;
                                           //   also L2-partials P[3][1M] at init
  u16*   Zbuf  = (u16*)t12;                //   gate [65536][384] bf16 (exact fit)
  u16*   Wbuf  = (u16*)(ws + 22020096);    // update Wt [1024][64][288] bf16
  u16*   Wbuf128 = Wbuf;                   // gate Wt [1024][128][288] bf16 (overlay)
  u16*   Btp   = (u16*)(ws + 31457280);    // [6144][1024] bf16
  u16*   Zt    = Wbuf;                     // overlay Wbuf+Btp: [24576][1024]
  float* acc1  = ws + 34603008;            // [n,b,128]
  float* acc0  = ws + 42991616;            // [n,b,128]
  u16*   LbStk = (u16*)(ws + 51380224);    // [2048][1024] bf16 (Lhi ; L2)
  u16*   chebb = (u16*)(ws + 52428800);    // [3][1024][1024] bf16
  float* s12   = ws + 54001664;
  float* s12u  = ws + 54001792;
  float* part0 = ws + 54001920;            // [64][16][128]
  float* part1 = ws + 54132992;
  float* rbuf  = ws + 54264064;            // [n,b,64]
  u16*   Vbg   = (u16*)(ws + 58458368);    // [384][96] = 18432 fl
  float* bag   = ws + 58476800;            // [384]
  u16*   Vbu   = (u16*)(ws + 58477184);    // [256][96] = 12288 fl
  float* bau   = ws + 58489472;            // [256]
  u16*   LhiT  = (u16*)(ws + 58489728);    // [1024][1024] bf16
  u16*   LloT  = (u16*)(ws + 59014016);    // [1024][1024] bf16
  u16*   Llo   = (u16*)(ws + 59538304);    // [1024][1024] bf16  (end 60,062,592)
  float* wpTg  = ws + 58489728;            // overlay LhiT+ (dead after l2p)
  float* wpTu  = ws + 59079552;

  dim3 blk(256);
  dim3 blk512(512);

  // ---- init ----
  split_hilo<<<1024, blk, 0, stream>>>(Ltil, LbStk, Llo, 262144);
  transpose_split<<<dim3(32, 32), blk, 0, stream>>>(Ltil, LhiT, LloT);
  mfma_l2p<<<dim3(16, 16, 3), blk, 0, stream>>>(LbStk, Llo, LhiT, LloT, t12);
  wpool_tr<<<dim3(9, 4, 16), blk, 0, stream>>>(g_wpool, wpTg, 128);
  wpool_tr<<<dim3(9, 2, 16), blk, 0, stream>>>(u_wpool, wpTu, 64);
  l2_finish<<<1024, blk, 0, stream>>>(t12, LbStk + 1048576);
  conv_f2b<<<3072, blk, 0, stream>>>(cheb, chebb, 786432);

  // ---- gate AVWGCN (dim_out = 128) ----
  concat_bf2<<<24576, blk, 0, stream>>>(x, state, inp, inpb);
  transpose_b2b<<<dim3(3, 32, 64), blk, 0, stream>>>(inpb, 96, 96, Btp);
  mfma_stack8<<<dim3(48, 16), blk512, 0, stream>>>(LbStk, Btp, t12, 6144);
  vgen2<128, 7><<<384, dim3(128), 0, stream>>>(g_gw, g_iw, g_ib, 384, Vbg, bag);
  weightgen5<36864><<<dim3(144, 16), blk, 0, stream>>>(emb, wpTg, Wbuf128);
  pernode10<128><<<1024, blk, 0, stream>>>(inp, t12, Wbuf128, emb, g_bpool, acc0);
  zgemm<<<dim3(3, 512), blk, 0, stream>>>(inpb, Vbg, bag, Zbuf, 384);   // overlays t12 (dead)
  transpose_b2b<<<dim3(12, 32, 64), blk, 0, stream>>>(Zbuf, 384, 384, Zt);  // kills Wbuf/Btp
  mfma_k3<<<dim3(64, 8), blk512, 0, stream>>>(chebb, Zt, g_gb, acc1, 8192, 7);
  att_reduce<128><<<dim3(16, 64), blk, 0, stream>>>(acc0, acc1, part0, part1);
  att_finish<128, 8><<<64, blk, 0, stream>>>(part0, part1, g_a1w1, g_a1w2, g_a2w1, g_a2w2, s12);
  gate_combine_b2<<<16384, blk, 0, stream>>>(acc0, acc1, s12, x, state, inp, inpb, rbuf);

  // ---- update AVWGCN (dim_out = 64), input = cand/candb ----
  transpose_b2b<<<dim3(3, 32, 64), blk, 0, stream>>>(inpb, 96, 96, Btp);
  mfma_stack8<<<dim3(48, 16), blk512, 0, stream>>>(LbStk, Btp, t12, 6144);
  vgen2<64, 6><<<256, dim3(128), 0, stream>>>(u_gw, u_iw, u_ib, 192, Vbu, bau);
  weightgen5<18432><<<dim3(72, 16), blk, 0, stream>>>(emb, wpTu, Wbuf);
  pernode10<64><<<1024, blk, 0, stream>>>(inp, t12, Wbuf, emb, u_bpool, acc0);
  zgemm<<<dim3(2, 512), blk, 0, stream>>>(inpb, Vbu, bau, Zbuf, 256);
  transpose_b2b<<<dim3(6, 32, 64), blk, 0, stream>>>(Zbuf, 256, 192, Zt);
  mfma_k3u<<<dim3(64, 8), blk512, 0, stream>>>(chebb, Zt, u_gb, acc1, 4096, 6);
  att_reduce<64><<<dim3(16, 64), blk, 0, stream>>>(acc0, acc1, part0, part1);
  att_finish<64, 4><<<64, blk, 0, stream>>>(part0, part1, u_a1w1, u_a1w2, u_a2w1, u_a2w2, s12u);
  final_h<<<16384, blk, 0, stream>>>(acc0, acc1, s12u, rbuf, state, out);
}